// Round 1
// baseline (1394.138 us; speedup 1.0000x reference)
//
#include <hip/hip_runtime.h>
#include <hip/hip_bf16.h>

#define NPTS 8192
#define KNN 64
#define EPSF 1e-7f

// ---------------- workspace layout (float offsets) ----------------
#define OFF_R       0
#define OFF_PX      8192
#define OFF_PY      16384
#define OFF_PZ      24576
#define OFF_STATS   32768          // s1:+0(128) s2:+128(256) s3:+384(512) s4:+896(2048)
#define OFF_FEATDN  36864          // N*4
#define OFF_EMB     69632          // embup 64*N then h2 128*N (contiguous 192*N)
#define OFF_H1      1642496        // 64*N
#define OFF_Y1      2166784        // 64*N
#define OFF_Y2      2691072        // 128*N
#define OFF_Y3      3739648        // 256*N
#define OFF_FEATUP  5836800        // N*K*4 ; reused as H3 (256*N) afterwards
#define OFF_WT1     7933952        // 4*64
#define OFF_WT2     7934208        // 64*128
#define OFF_WT3     7942400        // 192*256
#define OFF_WT4     7991552        // 256*1024  (end 8253696 floats ~ 31.5 MB)

__device__ __forceinline__ unsigned f2u(float f) {
    unsigned u = __float_as_uint(f);
    return ((int)u >= 0) ? (u | 0x80000000u) : ~u;
}
__device__ __forceinline__ unsigned long long u64min(unsigned long long a, unsigned long long b){ return a < b ? a : b; }
__device__ __forceinline__ unsigned long long u64max(unsigned long long a, unsigned long long b){ return a < b ? b : a; }

// ---------------- prep: SoA points, r, feat_down, weight transposes ----------------
__global__ __launch_bounds__(1024) void prep_kernel(
    const float* __restrict__ points,
    const float* __restrict__ c1w, const float* __restrict__ c2w,
    const float* __restrict__ c3w, const float* __restrict__ c4w,
    float* __restrict__ ws)
{
    float* pr = ws + OFF_R;
    float* px = ws + OFF_PX;
    float* py = ws + OFF_PY;
    float* pz = ws + OFF_PZ;
    float* featdn = ws + OFF_FEATDN;

    const int tid = threadIdx.x;
    unsigned long long mxk = 0ull, mnk = ~0ull;
    for (int n = tid; n < NPTS; n += 1024) {
        float x = points[3*n+0], y = points[3*n+1], z = points[3*n+2];
        px[n] = x; py[n] = y; pz[n] = z;
        float rr = x*x + y*y + z*z;
        pr[n] = rr;
        float vn = sqrtf(rr);
        unsigned b = __float_as_uint(vn);   // vn >= 0 -> bits monotone
        unsigned long long kmax = ((unsigned long long)b << 32) | (unsigned long long)(0xFFFFFFFFu - (unsigned)n);
        unsigned long long kmin = ((unsigned long long)b << 32) | (unsigned long long)(unsigned)n;
        mxk = u64max(mxk, kmax);
        mnk = u64min(mnk, kmin);
    }
    // wave reduce
    for (int j = 32; j > 0; j >>= 1) {
        mxk = u64max(mxk, __shfl_xor(mxk, j));
        mnk = u64min(mnk, __shfl_xor(mnk, j));
    }
    __shared__ unsigned long long smx[16], smn[16];
    int wid = tid >> 6;
    if ((tid & 63) == 0) { smx[wid] = mxk; smn[wid] = mnk; }
    __syncthreads();
    unsigned long long MX = 0ull, MN = ~0ull;
    for (int i = 0; i < 16; ++i) { MX = u64max(MX, smx[i]); MN = u64min(MN, smn[i]); }
    int i1 = (int)(0xFFFFFFFFu - (unsigned)(MX & 0xFFFFFFFFu));
    int i2 = (int)(unsigned)(MN & 0xFFFFFFFFu);

    float a1x = points[3*i1+0], a1y = points[3*i1+1], a1z = points[3*i1+2];
    float n1 = sqrtf(a1x*a1x + a1y*a1y + a1z*a1z) + EPSF;
    a1x /= n1; a1y /= n1; a1z /= n1;
    float a2x = points[3*i2+0], a2y = points[3*i2+1], a2z = points[3*i2+2];
    float n2 = sqrtf(a2x*a2x + a2y*a2y + a2z*a2z) + EPSF;
    a2x /= n2; a2y /= n2; a2z /= n2;
    float a3x = a1x + 1.5f*a2x, a3y = a1y + 1.5f*a2y, a3z = a1z + 1.5f*a2z;
    float n3 = sqrtf(a3x*a3x + a3y*a3y + a3z*a3z) + EPSF;
    a3x /= n3; a3y /= n3; a3z /= n3;

    for (int n = tid; n < NPTS; n += 1024) {
        float x = points[3*n+0], y = points[3*n+1], z = points[3*n+2];
        float vn = sqrtf(x*x + y*y + z*z);
        float den = vn + EPSF;
        float f1 = (x*a1x + y*a1y + z*a1z) / den;
        float f2 = (x*a2x + y*a2y + z*a2z) / den;
        float f3 = (x*a3x + y*a3y + z*a3z) / den;
        float4* f4 = (float4*)(featdn + 4*n);
        *f4 = make_float4(f1, f2, f3, vn);
    }

    // weight transposes: W[o][c] -> WT[c][o]
    float* wt1 = ws + OFF_WT1;
    for (int m = tid; m < 64*4; m += 1024)   { int o = m >> 2, c = m & 3;   wt1[c*64   + o] = c1w[m]; }
    float* wt2 = ws + OFF_WT2;
    for (int m = tid; m < 128*64; m += 1024) { int o = m >> 6, c = m & 63;  wt2[c*128  + o] = c2w[m]; }
    float* wt3 = ws + OFF_WT3;
    for (int m = tid; m < 256*192; m += 1024){ int o = m / 192, c = m % 192; wt3[c*256 + o] = c3w[m]; }
    float* wt4 = ws + OFF_WT4;
    for (int m = tid; m < 1024*256; m += 1024){ int o = m >> 8, c = m & 255; wt4[c*1024 + o] = c4w[m]; }
}

// ---------------- KNN + local rotation-invariant features ----------------
// grid 512 x 1024 threads; wave w handles query q = block*16 + w
__global__ __launch_bounds__(1024) void knn_feat_kernel(
    const float* __restrict__ px, const float* __restrict__ py,
    const float* __restrict__ pz, const float* __restrict__ pr,
    float4* __restrict__ feat_up)
{
    __shared__ float scx[2048], scy[2048], scz[2048], scr[2048];
    const int lane = threadIdx.x & 63;
    const int wid  = threadIdx.x >> 6;
    const int q = blockIdx.x * 16 + wid;

    const float qx = px[q], qy = py[q], qz = pz[q], qr = pr[q];
    unsigned long long cur = ~0ull;   // sorted ascending across lanes
    unsigned long long kth = ~0ull;   // cur @ lane 63

    for (int base = 0; base < NPTS; base += 2048) {
        __syncthreads();
        for (int t = threadIdx.x; t < 2048; t += 1024) {
            scx[t] = px[base + t]; scy[t] = py[base + t];
            scz[t] = pz[base + t]; scr[t] = pr[base + t];
        }
        __syncthreads();
        for (int sub = 0; sub < 2048; sub += 64) {
            int ci = sub + lane;
            float dot = qx*scx[ci] + qy*scy[ci] + qz*scz[ci];
            float d = qr - 2.f*dot + scr[ci];
            unsigned long long key = ((unsigned long long)f2u(d) << 32)
                                   | (unsigned long long)(unsigned)(base + ci);
            if (__ballot(key < kth)) {
                // bitonic sort 64 keys ascending across lanes
                for (int k = 2; k <= 64; k <<= 1) {
                    for (int j = k >> 1; j > 0; j >>= 1) {
                        unsigned long long o = __shfl_xor(key, j);
                        bool up = ((lane & k) == 0);
                        bool lower = ((lane & j) == 0);
                        key = (lower == up) ? u64min(key, o) : u64max(key, o);
                    }
                }
                // merge: keep 64 smallest of cur (asc) + key (asc)
                unsigned long long rev = __shfl(key, 63 - lane);
                unsigned long long m = u64min(cur, rev);     // bitonic
                for (int j = 32; j > 0; j >>= 1) {
                    unsigned long long o = __shfl_xor(m, j);
                    m = ((lane & j) == 0) ? u64min(m, o) : u64max(m, o);
                }
                cur = m;
                kth = __shfl(cur, 63);
            }
        }
    }

    // features: lane k = k-th nearest (distance-ascending order, idx tie-break = lax.top_k)
    int nidx = (int)(unsigned)(cur & 0xFFFFFFFFu);
    float cx = px[nidx], cy = py[nidx], cz = pz[nidx];
    float ox = __shfl(cx, 0), oy = __shfl(cy, 0), oz = __shfl(cz, 0);
    float pcx = cx - ox, pcy = cy - oy, pcz = cz - oz;
    float vn = sqrtf(pcx*pcx + pcy*pcy + pcz*pcz);

    // argmax vn over lanes, tie -> smaller lane
    unsigned long long ak = ((unsigned long long)__float_as_uint(vn) << 32)
                          | (unsigned long long)(unsigned)(63 - lane);
    for (int j = 32; j > 0; j >>= 1) ak = u64max(ak, __shfl_xor(ak, j));
    int id1 = 63 - (int)(unsigned)(ak & 0xFFFFFFFFu);

    float a1x = __shfl(pcx, id1), a1y = __shfl(pcy, id1), a1z = __shfl(pcz, id1);
    float n1 = sqrtf(a1x*a1x + a1y*a1y + a1z*a1z) + EPSF;
    a1x /= n1; a1y /= n1; a1z /= n1;

    float sx = pcx, sy = pcy, sz = pcz;
    for (int j = 32; j > 0; j >>= 1) {
        sx += __shfl_xor(sx, j); sy += __shfl_xor(sy, j); sz += __shfl_xor(sz, j);
    }
    float a2x = sx * (1.f/64.f), a2y = sy * (1.f/64.f), a2z = sz * (1.f/64.f);
    float n2 = sqrtf(a2x*a2x + a2y*a2y + a2z*a2z) + EPSF;
    a2x /= n2; a2y /= n2; a2z /= n2;

    float a3x = a1x + 1.5f*a2x, a3y = a1y + 1.5f*a2y, a3z = a1z + 1.5f*a2z;
    float n3 = sqrtf(a3x*a3x + a3y*a3y + a3z*a3z) + EPSF;
    a3x /= n3; a3y /= n3; a3z /= n3;

    float den = vn + EPSF;
    float f1 = (pcx*a1x + pcy*a1y + pcz*a1z) / den;
    float f2 = (pcx*a2x + pcy*a2y + pcz*a2z) / den;
    float f3 = (pcx*a3x + pcy*a3y + pcz*a3z) / den;
    feat_up[q*64 + lane] = make_float4(f1, f2, f3, vn);
}

// ---------------- 5-layer MLP + max over K ----------------
// block = 128 (2 waves), wave = one point, lane = neighbor
__global__ __launch_bounds__(128) void mlp_kernel(
    const float4* __restrict__ feat_up,
    const float* __restrict__ g0, const float* __restrict__ g1,
    const float* __restrict__ g2, const float* __restrict__ g3,
    const float* __restrict__ g4,
    float* __restrict__ embup)
{
    __shared__ float xt[2 * 64 * 65];
    const int lane = threadIdx.x & 63;
    const int wid  = threadIdx.x >> 6;
    const int q = blockIdx.x * 2 + wid;
    float* X = xt + wid * 64 * 65;

    float4 f = feat_up[q*64 + lane];
    float y[64];
    #pragma unroll
    for (int j = 0; j < 64; ++j) {
        float a = fmaf(f.x, g0[j], 0.f);
        a = fmaf(f.y, g0[64+j], a);
        a = fmaf(f.z, g0[128+j], a);
        a = fmaf(f.w, g0[192+j], a);
        y[j] = fmaxf(a, 0.f);
    }

    for (int l = 0; l < 4; ++l) {
        const float* w = (l==0) ? g1 : (l==1) ? g2 : (l==2) ? g3 : g4;
        #pragma unroll
        for (int j = 0; j < 64; ++j) X[lane*65 + j] = y[j];
        #pragma unroll
        for (int j = 0; j < 64; ++j) y[j] = 0.f;
        #pragma unroll 4
        for (int i = 0; i < 64; ++i) {
            float xi = X[lane*65 + i];
            #pragma unroll
            for (int j = 0; j < 64; ++j) y[j] = fmaf(xi, w[i*64 + j], y[j]);
        }
        #pragma unroll
        for (int j = 0; j < 64; ++j) y[j] = fmaxf(y[j], 0.f);
    }

    // max over K (rows of this wave's tile)
    #pragma unroll
    for (int j = 0; j < 64; ++j) X[lane*65 + j] = y[j];
    __syncthreads();
    float m = 0.f;  // all values are post-ReLU >= 0
    #pragma unroll
    for (int k = 0; k < 64; ++k) m = fmaxf(m, X[k*65 + lane]);
    embup[q*64 + lane] = m;
}

// ---------------- conv1x1 : y[o][p] = b[o] + sum_c WT[c][o] * x[c][p] ----------------
__global__ __launch_bounds__(256) void conv_kernel(
    const float* __restrict__ x, const float* __restrict__ wt,
    const float* __restrict__ bias, float* __restrict__ y, int C, int O)
{
    int p  = blockIdx.x * 256 + threadIdx.x;
    int o0 = blockIdx.y * 32;
    float acc[32];
    #pragma unroll
    for (int u = 0; u < 32; ++u) acc[u] = bias[o0 + u];
    for (int c = 0; c < C; ++c) {
        float xv = x[c * NPTS + p];
        const float* wr = wt + c * O + o0;
        #pragma unroll
        for (int u = 0; u < 32; ++u) acc[u] = fmaf(xv, wr[u], acc[u]);
    }
    #pragma unroll
    for (int u = 0; u < 32; ++u) y[(o0 + u) * NPTS + p] = acc[u];
}

// ---------------- per-channel sum / sumsq (one block per channel) ----------------
__global__ __launch_bounds__(256) void stats_kernel(
    const float* __restrict__ y, float* __restrict__ st)
{
    int c = blockIdx.x;
    float s = 0.f, ss = 0.f;
    for (int t = threadIdx.x; t < NPTS; t += 256) {
        float v = y[c * NPTS + t];
        s += v; ss += v * v;
    }
    for (int j = 32; j > 0; j >>= 1) { s += __shfl_xor(s, j); ss += __shfl_xor(ss, j); }
    __shared__ float ls[4], lss[4];
    int wid = threadIdx.x >> 6;
    if ((threadIdx.x & 63) == 0) { ls[wid] = s; lss[wid] = ss; }
    __syncthreads();
    if (threadIdx.x == 0) {
        float S  = ls[0]+ls[1]+ls[2]+ls[3];
        float SS = lss[0]+lss[1]+lss[2]+lss[3];
        st[c] = S;
        st[gridDim.x + c] = SS;
    }
}

// ---------------- BN (training batch stats) + ReLU ----------------
__global__ __launch_bounds__(256) void bnrelu_kernel(
    const float* y, const float* __restrict__ st,
    const float* __restrict__ g, const float* __restrict__ b,
    float* out, int C)
{
    int idx = blockIdx.x * 256 + threadIdx.x;
    int c = idx >> 13;   // N = 8192
    float mu  = st[c] * (1.f / 8192.f);
    float var = st[C + c] * (1.f / 8192.f) - mu * mu;
    float scale = g[c] / sqrtf(var + 1e-5f);
    float v = fmaf(y[idx] - mu, scale, b[c]);
    out[idx] = fmaxf(v, 0.f);
}

extern "C" void kernel_launch(void* const* d_in, const int* in_sizes, int n_in,
                              void* d_out, int out_size, void* d_ws, size_t ws_size,
                              hipStream_t stream) {
    const float* points = (const float*)d_in[0];
    const float* gw0 = (const float*)d_in[1];
    const float* gw1 = (const float*)d_in[2];
    const float* gw2 = (const float*)d_in[3];
    const float* gw3 = (const float*)d_in[4];
    const float* gw4 = (const float*)d_in[5];
    const float* c1w = (const float*)d_in[6];  const float* c1b = (const float*)d_in[7];
    const float* bn1g = (const float*)d_in[8]; const float* bn1b = (const float*)d_in[9];
    const float* c2w = (const float*)d_in[10]; const float* c2b = (const float*)d_in[11];
    const float* bn2g = (const float*)d_in[12];const float* bn2b = (const float*)d_in[13];
    const float* c3w = (const float*)d_in[14]; const float* c3b = (const float*)d_in[15];
    const float* bn3g = (const float*)d_in[16];const float* bn3b = (const float*)d_in[17];
    const float* c4w = (const float*)d_in[18]; const float* c4b = (const float*)d_in[19];
    const float* bn4g = (const float*)d_in[20];const float* bn4b = (const float*)d_in[21];

    float* ws = (float*)d_ws;
    float* px = ws + OFF_PX; float* py = ws + OFF_PY;
    float* pz = ws + OFF_PZ; float* pr = ws + OFF_R;
    float* featdn = ws + OFF_FEATDN;
    float* featup = ws + OFF_FEATUP;
    float* embup  = ws + OFF_EMB;              // first 64*N of emb region
    float* emb    = ws + OFF_EMB;              // 192*N contiguous
    float* h1 = ws + OFF_H1;
    float* h2 = ws + OFF_EMB + 64 * NPTS;      // channels 64..191 of emb
    float* h3 = ws + OFF_FEATUP;               // reuse feat_up region (exactly 256*N)
    float* y1 = ws + OFF_Y1; float* y2 = ws + OFF_Y2; float* y3 = ws + OFF_Y3;
    float* s1 = ws + OFF_STATS + 0;
    float* s2 = ws + OFF_STATS + 128;
    float* s3 = ws + OFF_STATS + 384;
    float* s4 = ws + OFF_STATS + 896;
    float* wt1 = ws + OFF_WT1; float* wt2 = ws + OFF_WT2;
    float* wt3 = ws + OFF_WT3; float* wt4 = ws + OFF_WT4;
    float* outp = (float*)d_out;

    prep_kernel<<<1, 1024, 0, stream>>>(points, c1w, c2w, c3w, c4w, ws);
    knn_feat_kernel<<<512, 1024, 0, stream>>>(px, py, pz, pr, (float4*)featup);
    mlp_kernel<<<4096, 128, 0, stream>>>((const float4*)featup, gw0, gw1, gw2, gw3, gw4, embup);

    conv_kernel<<<dim3(32, 2), 256, 0, stream>>>(featdn, wt1, c1b, y1, 4, 64);
    stats_kernel<<<64, 256, 0, stream>>>(y1, s1);
    bnrelu_kernel<<<64*32, 256, 0, stream>>>(y1, s1, bn1g, bn1b, h1, 64);

    conv_kernel<<<dim3(32, 4), 256, 0, stream>>>(h1, wt2, c2b, y2, 64, 128);
    stats_kernel<<<128, 256, 0, stream>>>(y2, s2);
    bnrelu_kernel<<<128*32, 256, 0, stream>>>(y2, s2, bn2g, bn2b, h2, 128);

    conv_kernel<<<dim3(32, 8), 256, 0, stream>>>(emb, wt3, c3b, y3, 192, 256);
    stats_kernel<<<256, 256, 0, stream>>>(y3, s3);
    bnrelu_kernel<<<256*32, 256, 0, stream>>>(y3, s3, bn3g, bn3b, h3, 256);

    conv_kernel<<<dim3(32, 32), 256, 0, stream>>>(h3, wt4, c4b, outp, 256, 1024);
    stats_kernel<<<1024, 256, 0, stream>>>(outp, s4);
    bnrelu_kernel<<<1024*32, 256, 0, stream>>>(outp, s4, bn4g, bn4b, outp, 1024);
}

// Round 2
// 723.781 us; speedup vs baseline: 1.9262x; 1.9262x over previous
//
#include <hip/hip_runtime.h>
#include <hip/hip_bf16.h>

#define NPTS 8192
#define KNN 64
#define EPSF 1e-7f

// ---------------- workspace layout (float offsets) ----------------
#define OFF_R       0
#define OFF_PX      8192
#define OFF_PY      16384
#define OFF_PZ      24576
#define OFF_STATS   32768          // s1:+0(128) s2:+128(256) s3:+384(512) s4:+896(2048)
#define OFF_AVEC    36000          // 9 floats a1,a2,a3
#define OFF_PART    36012          // 32 blocks x 2 u64 = 128 floats (even offset -> 8B aligned)
#define OFF_FEATDN  36864          // N*4
#define OFF_EMB     69632          // embup 64*N then h2 128*N (contiguous 192*N)
#define OFF_H1      1642496        // 64*N
#define OFF_Y1      2166784        // 64*N
#define OFF_Y2      2691072        // 128*N
#define OFF_Y3      3739648        // 256*N
#define OFF_FEATUP  5836800        // N*K*4 ; reused as H3 (256*N) afterwards
#define OFF_WT1     7933952        // 4*64
#define OFF_WT2     7934208        // 64*128
#define OFF_WT3     7942400        // 192*256
#define OFF_WT4     7991552        // 256*1024  (end 8253696 floats ~ 31.5 MB)

__device__ __forceinline__ unsigned f2u(float f) {
    unsigned u = __float_as_uint(f);
    return ((int)u >= 0) ? (u | 0x80000000u) : ~u;
}
__device__ __forceinline__ unsigned long long u64min(unsigned long long a, unsigned long long b){ return a < b ? a : b; }
__device__ __forceinline__ unsigned long long u64max(unsigned long long a, unsigned long long b){ return a < b ? b : a; }

// bitonic sort 64 keys ascending across lanes, then merge with cur (sorted asc),
// returning the 64 smallest (sorted asc).
__device__ __forceinline__ unsigned long long sort_merge(
    unsigned long long key, unsigned long long cur, int lane)
{
    #pragma unroll
    for (int k = 2; k <= 64; k <<= 1) {
        #pragma unroll
        for (int j = k >> 1; j > 0; j >>= 1) {
            unsigned long long o = __shfl_xor(key, j);
            bool up = ((lane & k) == 0);
            bool lower = ((lane & j) == 0);
            key = (lower == up) ? u64min(key, o) : u64max(key, o);
        }
    }
    unsigned long long rev = __shfl(key, 63 - lane);
    unsigned long long m = u64min(cur, rev);     // bitonic sequence
    #pragma unroll
    for (int j = 32; j > 0; j >>= 1) {
        unsigned long long o = __shfl_xor(m, j);
        m = ((lane & j) == 0) ? u64min(m, o) : u64max(m, o);
    }
    return m;
}

// ---------------- prep A: SoA points, r, per-block argmax/argmin partials ----------------
__global__ __launch_bounds__(256) void prep_a_kernel(
    const float* __restrict__ points, float* __restrict__ ws)
{
    const int n = blockIdx.x * 256 + threadIdx.x;   // grid 32 -> 8192 threads
    float x = points[3*n+0], y = points[3*n+1], z = points[3*n+2];
    ws[OFF_PX + n] = x; ws[OFF_PY + n] = y; ws[OFF_PZ + n] = z;
    float rr = x*x + y*y + z*z;
    ws[OFF_R + n] = rr;
    float vn = sqrtf(rr);
    unsigned b = __float_as_uint(vn);   // vn >= 0 -> bits monotone
    unsigned long long mxk = ((unsigned long long)b << 32) | (unsigned long long)(0xFFFFFFFFu - (unsigned)n);
    unsigned long long mnk = ((unsigned long long)b << 32) | (unsigned long long)(unsigned)n;
    for (int j = 32; j > 0; j >>= 1) {
        mxk = u64max(mxk, __shfl_xor(mxk, j));
        mnk = u64min(mnk, __shfl_xor(mnk, j));
    }
    __shared__ unsigned long long smx[4], smn[4];
    int wid = threadIdx.x >> 6;
    if ((threadIdx.x & 63) == 0) { smx[wid] = mxk; smn[wid] = mnk; }
    __syncthreads();
    if (threadIdx.x == 0) {
        unsigned long long MX = 0ull, MN = ~0ull;
        for (int i = 0; i < 4; ++i) { MX = u64max(MX, smx[i]); MN = u64min(MN, smn[i]); }
        unsigned long long* parts = (unsigned long long*)(ws + OFF_PART);
        parts[2*blockIdx.x + 0] = MX;
        parts[2*blockIdx.x + 1] = MN;
    }
}

// ---------------- prep B: reduce partials, compute a1/a2/a3 ----------------
__global__ __launch_bounds__(64) void prep_b_kernel(
    const float* __restrict__ points, float* __restrict__ ws)
{
    const int lane = threadIdx.x;
    const unsigned long long* parts = (const unsigned long long*)(ws + OFF_PART);
    unsigned long long mxk = (lane < 32) ? parts[2*lane + 0] : 0ull;
    unsigned long long mnk = (lane < 32) ? parts[2*lane + 1] : ~0ull;
    for (int j = 32; j > 0; j >>= 1) {
        mxk = u64max(mxk, __shfl_xor(mxk, j));
        mnk = u64min(mnk, __shfl_xor(mnk, j));
    }
    if (lane == 0) {
        int i1 = (int)(0xFFFFFFFFu - (unsigned)(mxk & 0xFFFFFFFFu));
        int i2 = (int)(unsigned)(mnk & 0xFFFFFFFFu);
        float a1x = points[3*i1+0], a1y = points[3*i1+1], a1z = points[3*i1+2];
        float n1 = sqrtf(a1x*a1x + a1y*a1y + a1z*a1z) + EPSF;
        a1x /= n1; a1y /= n1; a1z /= n1;
        float a2x = points[3*i2+0], a2y = points[3*i2+1], a2z = points[3*i2+2];
        float n2 = sqrtf(a2x*a2x + a2y*a2y + a2z*a2z) + EPSF;
        a2x /= n2; a2y /= n2; a2z /= n2;
        float a3x = a1x + 1.5f*a2x, a3y = a1y + 1.5f*a2y, a3z = a1z + 1.5f*a2z;
        float n3 = sqrtf(a3x*a3x + a3y*a3y + a3z*a3z) + EPSF;
        a3x /= n3; a3y /= n3; a3z /= n3;
        float* av = ws + OFF_AVEC;
        av[0]=a1x; av[1]=a1y; av[2]=a1z;
        av[3]=a2x; av[4]=a2y; av[5]=a2z;
        av[6]=a3x; av[7]=a3y; av[8]=a3z;
    }
}

// ---------------- prep C: feat_down ----------------
__global__ __launch_bounds__(256) void prep_c_kernel(float* __restrict__ ws)
{
    const int n = blockIdx.x * 256 + threadIdx.x;   // grid 32
    const float* av = ws + OFF_AVEC;
    float x = ws[OFF_PX + n], y = ws[OFF_PY + n], z = ws[OFF_PZ + n];
    float vn = sqrtf(x*x + y*y + z*z);
    float den = vn + EPSF;
    float f1 = (x*av[0] + y*av[1] + z*av[2]) / den;
    float f2 = (x*av[3] + y*av[4] + z*av[5]) / den;
    float f3 = (x*av[6] + y*av[7] + z*av[8]) / den;
    float4* f4 = (float4*)(ws + OFF_FEATDN + 4*n);
    *f4 = make_float4(f1, f2, f3, vn);
}

// ---------------- weight transposes: W[o][c] -> WT[c][o] ----------------
__global__ __launch_bounds__(256) void wt_kernel(
    const float* __restrict__ c1w, const float* __restrict__ c2w,
    const float* __restrict__ c3w, const float* __restrict__ c4w,
    float* __restrict__ ws)
{
    const int t = blockIdx.x * 256 + threadIdx.x;
    const int T = gridDim.x * 256;
    for (int m = t; m < 64*4; m += T)    { int o = m >> 2, c = m & 3;       ws[OFF_WT1 + c*64   + o] = c1w[m]; }
    for (int m = t; m < 128*64; m += T)  { int o = m >> 6, c = m & 63;      ws[OFF_WT2 + c*128  + o] = c2w[m]; }
    for (int m = t; m < 256*192; m += T) { int o = m / 192, c = m - o*192;  ws[OFF_WT3 + c*256  + o] = c3w[m]; }
    for (int m = t; m < 1024*256; m += T){ int o = m >> 8, c = m & 255;     ws[OFF_WT4 + c*1024 + o] = c4w[m]; }
}

// ---------------- KNN + local rotation-invariant features ----------------
// grid 512 x 1024 threads; wave w handles query q = block*16 + w.
// Filter-then-sort: candidates beating kth are compacted into an LDS queue;
// sort+merge fires only when >=64 queued (~6 times total vs 128 chunks).
__global__ __launch_bounds__(1024) void knn_feat_kernel(
    const float* __restrict__ px, const float* __restrict__ py,
    const float* __restrict__ pz, const float* __restrict__ pr,
    float4* __restrict__ feat_up)
{
    __shared__ float scx[2048], scy[2048], scz[2048], scr[2048];
    __shared__ unsigned long long queue[16][128];
    const int lane = threadIdx.x & 63;
    const int wid  = threadIdx.x >> 6;
    const int q = blockIdx.x * 16 + wid;
    unsigned long long* Q = queue[wid];

    const float qx = px[q], qy = py[q], qz = pz[q], qr = pr[q];
    unsigned long long cur = ~0ull;   // sorted ascending across lanes
    unsigned long long kth = ~0ull;   // cur @ lane 63
    int qcount = 0;

    for (int base = 0; base < NPTS; base += 2048) {
        __syncthreads();
        for (int t = threadIdx.x; t < 2048; t += 1024) {
            scx[t] = px[base + t]; scy[t] = py[base + t];
            scz[t] = pz[base + t]; scr[t] = pr[base + t];
        }
        __syncthreads();
        for (int sub = 0; sub < 2048; sub += 64) {
            int ci = sub + lane;
            float dot = qx*scx[ci] + qy*scy[ci] + qz*scz[ci];
            float d = qr - 2.f*dot + scr[ci];
            unsigned long long key = ((unsigned long long)f2u(d) << 32)
                                   | (unsigned long long)(unsigned)(base + ci);
            bool pass = key < kth;
            unsigned long long mask = __ballot(pass);
            if (mask) {
                int prefix = __builtin_amdgcn_mbcnt_hi((unsigned)(mask >> 32),
                              __builtin_amdgcn_mbcnt_lo((unsigned)mask, 0));
                if (pass) Q[qcount + prefix] = key;
                qcount += __popcll(mask);
                if (qcount >= 64) {
                    qcount -= 64;
                    unsigned long long batch = Q[qcount + lane];
                    cur = sort_merge(batch, cur, lane);
                    kth = __shfl(cur, 63);
                }
            }
        }
    }
    // drain remaining (< 64) queued candidates
    {
        unsigned long long batch = (lane < qcount) ? Q[lane] : ~0ull;
        cur = sort_merge(batch, cur, lane);
    }

    // features: lane k = k-th nearest (distance-ascending order, idx tie-break = lax.top_k)
    int nidx = (int)(unsigned)(cur & 0xFFFFFFFFu);
    float cx = px[nidx], cy = py[nidx], cz = pz[nidx];
    float ox = __shfl(cx, 0), oy = __shfl(cy, 0), oz = __shfl(cz, 0);
    float pcx = cx - ox, pcy = cy - oy, pcz = cz - oz;
    float vn = sqrtf(pcx*pcx + pcy*pcy + pcz*pcz);

    // argmax vn over lanes, tie -> smaller lane
    unsigned long long ak = ((unsigned long long)__float_as_uint(vn) << 32)
                          | (unsigned long long)(unsigned)(63 - lane);
    for (int j = 32; j > 0; j >>= 1) ak = u64max(ak, __shfl_xor(ak, j));
    int id1 = 63 - (int)(unsigned)(ak & 0xFFFFFFFFu);

    float a1x = __shfl(pcx, id1), a1y = __shfl(pcy, id1), a1z = __shfl(pcz, id1);
    float n1 = sqrtf(a1x*a1x + a1y*a1y + a1z*a1z) + EPSF;
    a1x /= n1; a1y /= n1; a1z /= n1;

    float sx = pcx, sy = pcy, sz = pcz;
    for (int j = 32; j > 0; j >>= 1) {
        sx += __shfl_xor(sx, j); sy += __shfl_xor(sy, j); sz += __shfl_xor(sz, j);
    }
    float a2x = sx * (1.f/64.f), a2y = sy * (1.f/64.f), a2z = sz * (1.f/64.f);
    float n2 = sqrtf(a2x*a2x + a2y*a2y + a2z*a2z) + EPSF;
    a2x /= n2; a2y /= n2; a2z /= n2;

    float a3x = a1x + 1.5f*a2x, a3y = a1y + 1.5f*a2y, a3z = a1z + 1.5f*a2z;
    float n3 = sqrtf(a3x*a3x + a3y*a3y + a3z*a3z) + EPSF;
    a3x /= n3; a3y /= n3; a3z /= n3;

    float den = vn + EPSF;
    float f1 = (pcx*a1x + pcy*a1y + pcz*a1z) / den;
    float f2 = (pcx*a2x + pcy*a2y + pcz*a2z) / den;
    float f3 = (pcx*a3x + pcy*a3y + pcz*a3z) / den;
    feat_up[q*64 + lane] = make_float4(f1, f2, f3, vn);
}

// ---------------- 5-layer MLP + max over K ----------------
// block = 128 (2 waves), wave = one point, lane = neighbor
__global__ __launch_bounds__(128) void mlp_kernel(
    const float4* __restrict__ feat_up,
    const float* __restrict__ g0, const float* __restrict__ g1,
    const float* __restrict__ g2, const float* __restrict__ g3,
    const float* __restrict__ g4,
    float* __restrict__ embup)
{
    __shared__ float xt[2 * 64 * 65];
    const int lane = threadIdx.x & 63;
    const int wid  = threadIdx.x >> 6;
    const int q = blockIdx.x * 2 + wid;
    float* X = xt + wid * 64 * 65;

    float4 f = feat_up[q*64 + lane];
    float y[64];
    #pragma unroll
    for (int j = 0; j < 64; ++j) {
        float a = fmaf(f.x, g0[j], 0.f);
        a = fmaf(f.y, g0[64+j], a);
        a = fmaf(f.z, g0[128+j], a);
        a = fmaf(f.w, g0[192+j], a);
        y[j] = fmaxf(a, 0.f);
    }

    for (int l = 0; l < 4; ++l) {
        const float* w = (l==0) ? g1 : (l==1) ? g2 : (l==2) ? g3 : g4;
        #pragma unroll
        for (int j = 0; j < 64; ++j) X[lane*65 + j] = y[j];
        #pragma unroll
        for (int j = 0; j < 64; ++j) y[j] = 0.f;
        #pragma unroll 4
        for (int i = 0; i < 64; ++i) {
            float xi = X[lane*65 + i];
            #pragma unroll
            for (int j = 0; j < 64; ++j) y[j] = fmaf(xi, w[i*64 + j], y[j]);
        }
        #pragma unroll
        for (int j = 0; j < 64; ++j) y[j] = fmaxf(y[j], 0.f);
    }

    // max over K (rows of this wave's tile)
    #pragma unroll
    for (int j = 0; j < 64; ++j) X[lane*65 + j] = y[j];
    __syncthreads();
    float m = 0.f;  // all values are post-ReLU >= 0
    #pragma unroll
    for (int k = 0; k < 64; ++k) m = fmaxf(m, X[k*65 + lane]);
    embup[q*64 + lane] = m;
}

// ---------------- conv1x1 : y[o][p] = b[o] + sum_c WT[c][o] * x[c][p] ----------------
__global__ __launch_bounds__(256) void conv_kernel(
    const float* __restrict__ x, const float* __restrict__ wt,
    const float* __restrict__ bias, float* __restrict__ y, int C, int O)
{
    int p  = blockIdx.x * 256 + threadIdx.x;
    int o0 = blockIdx.y * 32;
    float acc[32];
    #pragma unroll
    for (int u = 0; u < 32; ++u) acc[u] = bias[o0 + u];
    for (int c = 0; c < C; ++c) {
        float xv = x[c * NPTS + p];
        const float* wr = wt + c * O + o0;
        #pragma unroll
        for (int u = 0; u < 32; ++u) acc[u] = fmaf(xv, wr[u], acc[u]);
    }
    #pragma unroll
    for (int u = 0; u < 32; ++u) y[(o0 + u) * NPTS + p] = acc[u];
}

// ---------------- per-channel sum / sumsq (one block per channel) ----------------
__global__ __launch_bounds__(256) void stats_kernel(
    const float* __restrict__ y, float* __restrict__ st)
{
    int c = blockIdx.x;
    float s = 0.f, ss = 0.f;
    for (int t = threadIdx.x; t < NPTS; t += 256) {
        float v = y[c * NPTS + t];
        s += v; ss += v * v;
    }
    for (int j = 32; j > 0; j >>= 1) { s += __shfl_xor(s, j); ss += __shfl_xor(ss, j); }
    __shared__ float ls[4], lss[4];
    int wid = threadIdx.x >> 6;
    if ((threadIdx.x & 63) == 0) { ls[wid] = s; lss[wid] = ss; }
    __syncthreads();
    if (threadIdx.x == 0) {
        float S  = ls[0]+ls[1]+ls[2]+ls[3];
        float SS = lss[0]+lss[1]+lss[2]+lss[3];
        st[c] = S;
        st[gridDim.x + c] = SS;
    }
}

// ---------------- BN (training batch stats) + ReLU ----------------
__global__ __launch_bounds__(256) void bnrelu_kernel(
    const float* y, const float* __restrict__ st,
    const float* __restrict__ g, const float* __restrict__ b,
    float* out, int C)
{
    int idx = blockIdx.x * 256 + threadIdx.x;
    int c = idx >> 13;   // N = 8192
    float mu  = st[c] * (1.f / 8192.f);
    float var = st[C + c] * (1.f / 8192.f) - mu * mu;
    float scale = g[c] / sqrtf(var + 1e-5f);
    float v = fmaf(y[idx] - mu, scale, b[c]);
    out[idx] = fmaxf(v, 0.f);
}

extern "C" void kernel_launch(void* const* d_in, const int* in_sizes, int n_in,
                              void* d_out, int out_size, void* d_ws, size_t ws_size,
                              hipStream_t stream) {
    const float* points = (const float*)d_in[0];
    const float* gw0 = (const float*)d_in[1];
    const float* gw1 = (const float*)d_in[2];
    const float* gw2 = (const float*)d_in[3];
    const float* gw3 = (const float*)d_in[4];
    const float* gw4 = (const float*)d_in[5];
    const float* c1w = (const float*)d_in[6];  const float* c1b = (const float*)d_in[7];
    const float* bn1g = (const float*)d_in[8]; const float* bn1b = (const float*)d_in[9];
    const float* c2w = (const float*)d_in[10]; const float* c2b = (const float*)d_in[11];
    const float* bn2g = (const float*)d_in[12];const float* bn2b = (const float*)d_in[13];
    const float* c3w = (const float*)d_in[14]; const float* c3b = (const float*)d_in[15];
    const float* bn3g = (const float*)d_in[16];const float* bn3b = (const float*)d_in[17];
    const float* c4w = (const float*)d_in[18]; const float* c4b = (const float*)d_in[19];
    const float* bn4g = (const float*)d_in[20];const float* bn4b = (const float*)d_in[21];

    float* ws = (float*)d_ws;
    float* px = ws + OFF_PX; float* py = ws + OFF_PY;
    float* pz = ws + OFF_PZ; float* pr = ws + OFF_R;
    float* featdn = ws + OFF_FEATDN;
    float* featup = ws + OFF_FEATUP;
    float* embup  = ws + OFF_EMB;              // first 64*N of emb region
    float* emb    = ws + OFF_EMB;              // 192*N contiguous
    float* h1 = ws + OFF_H1;
    float* h2 = ws + OFF_EMB + 64 * NPTS;      // channels 64..191 of emb
    float* h3 = ws + OFF_FEATUP;               // reuse feat_up region (exactly 256*N)
    float* y1 = ws + OFF_Y1; float* y2 = ws + OFF_Y2; float* y3 = ws + OFF_Y3;
    float* s1 = ws + OFF_STATS + 0;
    float* s2 = ws + OFF_STATS + 128;
    float* s3 = ws + OFF_STATS + 384;
    float* s4 = ws + OFF_STATS + 896;
    float* wt1 = ws + OFF_WT1; float* wt2 = ws + OFF_WT2;
    float* wt3 = ws + OFF_WT3; float* wt4 = ws + OFF_WT4;
    float* outp = (float*)d_out;

    prep_a_kernel<<<32, 256, 0, stream>>>(points, ws);
    prep_b_kernel<<<1, 64, 0, stream>>>(points, ws);
    prep_c_kernel<<<32, 256, 0, stream>>>(ws);
    wt_kernel<<<256, 256, 0, stream>>>(c1w, c2w, c3w, c4w, ws);

    knn_feat_kernel<<<512, 1024, 0, stream>>>(px, py, pz, pr, (float4*)featup);
    mlp_kernel<<<4096, 128, 0, stream>>>((const float4*)featup, gw0, gw1, gw2, gw3, gw4, embup);

    conv_kernel<<<dim3(32, 2), 256, 0, stream>>>(featdn, wt1, c1b, y1, 4, 64);
    stats_kernel<<<64, 256, 0, stream>>>(y1, s1);
    bnrelu_kernel<<<64*32, 256, 0, stream>>>(y1, s1, bn1g, bn1b, h1, 64);

    conv_kernel<<<dim3(32, 4), 256, 0, stream>>>(h1, wt2, c2b, y2, 64, 128);
    stats_kernel<<<128, 256, 0, stream>>>(y2, s2);
    bnrelu_kernel<<<128*32, 256, 0, stream>>>(y2, s2, bn2g, bn2b, h2, 128);

    conv_kernel<<<dim3(32, 8), 256, 0, stream>>>(emb, wt3, c3b, y3, 192, 256);
    stats_kernel<<<256, 256, 0, stream>>>(y3, s3);
    bnrelu_kernel<<<256*32, 256, 0, stream>>>(y3, s3, bn3g, bn3b, h3, 256);

    conv_kernel<<<dim3(32, 32), 256, 0, stream>>>(h3, wt4, c4b, outp, 256, 1024);
    stats_kernel<<<1024, 256, 0, stream>>>(outp, s4);
    bnrelu_kernel<<<1024*32, 256, 0, stream>>>(outp, s4, bn4g, bn4b, outp, 1024);
}

// Round 3
// 486.110 us; speedup vs baseline: 2.8679x; 1.4889x over previous
//
#include <hip/hip_runtime.h>
#include <hip/hip_bf16.h>

#define NPTS 8192
#define KNN 64
#define EPSF 1e-7f

// ---------------- workspace layout (float offsets) ----------------
#define OFF_R       0
#define OFF_PX      8192
#define OFF_PY      16384
#define OFF_PZ      24576
#define OFF_STATS   32768          // s1:+0(128) s2:+128(256) s3:+384(512) s4:+896(2048)
#define OFF_AVEC    36000          // 9 floats a1,a2,a3
#define OFF_PART    36012          // 32 blocks x 2 u64 = 128 floats
#define OFF_FEATDN  36864          // N*4
#define OFF_EMB     69632          // embup 64*N then h2 128*N (contiguous 192*N)
#define OFF_H1      1642496        // 64*N
#define OFF_Y1      2166784        // 64*N
#define OFF_Y2      2691072        // 128*N
#define OFF_Y3      3739648        // 256*N ; gwT bf16 parked here until conv3 runs
#define OFF_FEATUP  5836800        // N*K*4 ; reused as H3 (256*N) afterwards
#define OFF_WT1     7933952        // 4*64
#define OFF_WT2     7934208        // 64*128
#define OFF_WT3     7942400        // 192*256
#define OFF_WT4     7991552        // 256*1024

typedef __bf16 bf16x8 __attribute__((ext_vector_type(8)));
typedef float  f32x4  __attribute__((ext_vector_type(4)));

__device__ __forceinline__ unsigned f2u(float f) {
    unsigned u = __float_as_uint(f);
    return ((int)u >= 0) ? (u | 0x80000000u) : ~u;
}
__device__ __forceinline__ unsigned short f2bf(float x) {
    unsigned u = __float_as_uint(x);
    unsigned r = (u + 0x7FFFu + ((u >> 16) & 1u)) >> 16;   // RNE
    return (unsigned short)r;
}
__device__ __forceinline__ unsigned long long u64min(unsigned long long a, unsigned long long b){ return a < b ? a : b; }
__device__ __forceinline__ unsigned long long u64max(unsigned long long a, unsigned long long b){ return a < b ? b : a; }

// bitonic sort 64 keys ascending across lanes, then merge with cur (sorted asc),
// returning the 64 smallest (sorted asc).
__device__ __forceinline__ unsigned long long sort_merge(
    unsigned long long key, unsigned long long cur, int lane)
{
    #pragma unroll
    for (int k = 2; k <= 64; k <<= 1) {
        #pragma unroll
        for (int j = k >> 1; j > 0; j >>= 1) {
            unsigned long long o = __shfl_xor(key, j);
            bool up = ((lane & k) == 0);
            bool lower = ((lane & j) == 0);
            key = (lower == up) ? u64min(key, o) : u64max(key, o);
        }
    }
    unsigned long long rev = __shfl(key, 63 - lane);
    unsigned long long m = u64min(cur, rev);     // bitonic sequence
    #pragma unroll
    for (int j = 32; j > 0; j >>= 1) {
        unsigned long long o = __shfl_xor(m, j);
        m = ((lane & j) == 0) ? u64min(m, o) : u64max(m, o);
    }
    return m;
}

// ---------------- prep A: SoA points, r, per-block argmax/argmin partials ----------------
__global__ __launch_bounds__(256) void prep_a_kernel(
    const float* __restrict__ points, float* __restrict__ ws)
{
    const int n = blockIdx.x * 256 + threadIdx.x;
    float x = points[3*n+0], y = points[3*n+1], z = points[3*n+2];
    ws[OFF_PX + n] = x; ws[OFF_PY + n] = y; ws[OFF_PZ + n] = z;
    float rr = x*x + y*y + z*z;
    ws[OFF_R + n] = rr;
    float vn = sqrtf(rr);
    unsigned b = __float_as_uint(vn);
    unsigned long long mxk = ((unsigned long long)b << 32) | (unsigned long long)(0xFFFFFFFFu - (unsigned)n);
    unsigned long long mnk = ((unsigned long long)b << 32) | (unsigned long long)(unsigned)n;
    for (int j = 32; j > 0; j >>= 1) {
        mxk = u64max(mxk, __shfl_xor(mxk, j));
        mnk = u64min(mnk, __shfl_xor(mnk, j));
    }
    __shared__ unsigned long long smx[4], smn[4];
    int wid = threadIdx.x >> 6;
    if ((threadIdx.x & 63) == 0) { smx[wid] = mxk; smn[wid] = mnk; }
    __syncthreads();
    if (threadIdx.x == 0) {
        unsigned long long MX = 0ull, MN = ~0ull;
        for (int i = 0; i < 4; ++i) { MX = u64max(MX, smx[i]); MN = u64min(MN, smn[i]); }
        unsigned long long* parts = (unsigned long long*)(ws + OFF_PART);
        parts[2*blockIdx.x + 0] = MX;
        parts[2*blockIdx.x + 1] = MN;
    }
}

// ---------------- prep B: reduce partials, compute a1/a2/a3 ----------------
__global__ __launch_bounds__(64) void prep_b_kernel(
    const float* __restrict__ points, float* __restrict__ ws)
{
    const int lane = threadIdx.x;
    const unsigned long long* parts = (const unsigned long long*)(ws + OFF_PART);
    unsigned long long mxk = (lane < 32) ? parts[2*lane + 0] : 0ull;
    unsigned long long mnk = (lane < 32) ? parts[2*lane + 1] : ~0ull;
    for (int j = 32; j > 0; j >>= 1) {
        mxk = u64max(mxk, __shfl_xor(mxk, j));
        mnk = u64min(mnk, __shfl_xor(mnk, j));
    }
    if (lane == 0) {
        int i1 = (int)(0xFFFFFFFFu - (unsigned)(mxk & 0xFFFFFFFFu));
        int i2 = (int)(unsigned)(mnk & 0xFFFFFFFFu);
        float a1x = points[3*i1+0], a1y = points[3*i1+1], a1z = points[3*i1+2];
        float n1 = sqrtf(a1x*a1x + a1y*a1y + a1z*a1z) + EPSF;
        a1x /= n1; a1y /= n1; a1z /= n1;
        float a2x = points[3*i2+0], a2y = points[3*i2+1], a2z = points[3*i2+2];
        float n2 = sqrtf(a2x*a2x + a2y*a2y + a2z*a2z) + EPSF;
        a2x /= n2; a2y /= n2; a2z /= n2;
        float a3x = a1x + 1.5f*a2x, a3y = a1y + 1.5f*a2y, a3z = a1z + 1.5f*a2z;
        float n3 = sqrtf(a3x*a3x + a3y*a3y + a3z*a3z) + EPSF;
        a3x /= n3; a3y /= n3; a3z /= n3;
        float* av = ws + OFF_AVEC;
        av[0]=a1x; av[1]=a1y; av[2]=a1z;
        av[3]=a2x; av[4]=a2y; av[5]=a2z;
        av[6]=a3x; av[7]=a3y; av[8]=a3z;
    }
}

// ---------------- prep C: feat_down ----------------
__global__ __launch_bounds__(256) void prep_c_kernel(float* __restrict__ ws)
{
    const int n = blockIdx.x * 256 + threadIdx.x;
    const float* av = ws + OFF_AVEC;
    float x = ws[OFF_PX + n], y = ws[OFF_PY + n], z = ws[OFF_PZ + n];
    float vn = sqrtf(x*x + y*y + z*z);
    float den = vn + EPSF;
    float f1 = (x*av[0] + y*av[1] + z*av[2]) / den;
    float f2 = (x*av[3] + y*av[4] + z*av[5]) / den;
    float f3 = (x*av[6] + y*av[7] + z*av[8]) / den;
    float4* f4 = (float4*)(ws + OFF_FEATDN + 4*n);
    *f4 = make_float4(f1, f2, f3, vn);
}

// ---------------- weight transposes + bf16 MLP weight transposes ----------------
// conv WT[c][o] = W[o][c]; MLP gwT[o][i] = bf16(gw[i][o]) (layer0 zero-padded to K=32)
__global__ __launch_bounds__(256) void wt_kernel(
    const float* __restrict__ c1w, const float* __restrict__ c2w,
    const float* __restrict__ c3w, const float* __restrict__ c4w,
    const float* __restrict__ gw0, const float* __restrict__ gw1,
    const float* __restrict__ gw2, const float* __restrict__ gw3,
    const float* __restrict__ gw4,
    float* __restrict__ ws)
{
    const int t = blockIdx.x * 256 + threadIdx.x;
    const int T = gridDim.x * 256;
    for (int m = t; m < 64*4; m += T)    { int o = m >> 2, c = m & 3;       ws[OFF_WT1 + c*64   + o] = c1w[m]; }
    for (int m = t; m < 128*64; m += T)  { int o = m >> 6, c = m & 63;      ws[OFF_WT2 + c*128  + o] = c2w[m]; }
    for (int m = t; m < 256*192; m += T) { int o = m / 192, c = m - o*192;  ws[OFF_WT3 + c*256  + o] = c3w[m]; }
    for (int m = t; m < 1024*256; m += T){ int o = m >> 8, c = m & 255;     ws[OFF_WT4 + c*1024 + o] = c4w[m]; }

    unsigned short* gwt = (unsigned short*)(ws + OFF_Y3);
    for (int m = t; m < 2048; m += T) {          // gw0T padded [64][32]
        int o = m >> 5, i = m & 31;
        gwt[m] = (i < 4) ? f2bf(gw0[i*64 + o]) : (unsigned short)0;
    }
    const float* gsrc[4] = {gw1, gw2, gw3, gw4};
    for (int l = 0; l < 4; ++l) {
        const float* g = gsrc[l];
        unsigned short* dst = gwt + 2048 + l*4096;
        for (int m = t; m < 4096; m += T) { int o = m >> 6, i = m & 63; dst[m] = f2bf(g[i*64 + o]); }
    }
}

// ---------------- KNN + local rotation-invariant features ----------------
__global__ __launch_bounds__(1024) void knn_feat_kernel(
    const float* __restrict__ px, const float* __restrict__ py,
    const float* __restrict__ pz, const float* __restrict__ pr,
    float4* __restrict__ feat_up)
{
    __shared__ float scx[2048], scy[2048], scz[2048], scr[2048];
    __shared__ unsigned long long queue[16][128];
    const int lane = threadIdx.x & 63;
    const int wid  = threadIdx.x >> 6;
    const int q = blockIdx.x * 16 + wid;
    unsigned long long* Q = queue[wid];

    const float qx = px[q], qy = py[q], qz = pz[q], qr = pr[q];
    unsigned long long cur = ~0ull;
    unsigned long long kth = ~0ull;
    int qcount = 0;

    for (int base = 0; base < NPTS; base += 2048) {
        __syncthreads();
        for (int t = threadIdx.x; t < 2048; t += 1024) {
            scx[t] = px[base + t]; scy[t] = py[base + t];
            scz[t] = pz[base + t]; scr[t] = pr[base + t];
        }
        __syncthreads();
        for (int sub = 0; sub < 2048; sub += 64) {
            int ci = sub + lane;
            float dot = qx*scx[ci] + qy*scy[ci] + qz*scz[ci];
            float d = qr - 2.f*dot + scr[ci];
            unsigned long long key = ((unsigned long long)f2u(d) << 32)
                                   | (unsigned long long)(unsigned)(base + ci);
            bool pass = key < kth;
            unsigned long long mask = __ballot(pass);
            if (mask) {
                int prefix = __builtin_amdgcn_mbcnt_hi((unsigned)(mask >> 32),
                              __builtin_amdgcn_mbcnt_lo((unsigned)mask, 0));
                if (pass) Q[qcount + prefix] = key;
                qcount += __popcll(mask);
                if (qcount >= 64) {
                    qcount -= 64;
                    unsigned long long batch = Q[qcount + lane];
                    cur = sort_merge(batch, cur, lane);
                    kth = __shfl(cur, 63);
                }
            }
        }
    }
    {
        unsigned long long batch = (lane < qcount) ? Q[lane] : ~0ull;
        cur = sort_merge(batch, cur, lane);
    }

    int nidx = (int)(unsigned)(cur & 0xFFFFFFFFu);
    float cx = px[nidx], cy = py[nidx], cz = pz[nidx];
    float ox = __shfl(cx, 0), oy = __shfl(cy, 0), oz = __shfl(cz, 0);
    float pcx = cx - ox, pcy = cy - oy, pcz = cz - oz;
    float vn = sqrtf(pcx*pcx + pcy*pcy + pcz*pcz);

    unsigned long long ak = ((unsigned long long)__float_as_uint(vn) << 32)
                          | (unsigned long long)(unsigned)(63 - lane);
    for (int j = 32; j > 0; j >>= 1) ak = u64max(ak, __shfl_xor(ak, j));
    int id1 = 63 - (int)(unsigned)(ak & 0xFFFFFFFFu);

    float a1x = __shfl(pcx, id1), a1y = __shfl(pcy, id1), a1z = __shfl(pcz, id1);
    float n1 = sqrtf(a1x*a1x + a1y*a1y + a1z*a1z) + EPSF;
    a1x /= n1; a1y /= n1; a1z /= n1;

    float sx = pcx, sy = pcy, sz = pcz;
    for (int j = 32; j > 0; j >>= 1) {
        sx += __shfl_xor(sx, j); sy += __shfl_xor(sy, j); sz += __shfl_xor(sz, j);
    }
    float a2x = sx * (1.f/64.f), a2y = sy * (1.f/64.f), a2z = sz * (1.f/64.f);
    float n2 = sqrtf(a2x*a2x + a2y*a2y + a2z*a2z) + EPSF;
    a2x /= n2; a2y /= n2; a2z /= n2;

    float a3x = a1x + 1.5f*a2x, a3y = a1y + 1.5f*a2y, a3z = a1z + 1.5f*a2z;
    float n3 = sqrtf(a3x*a3x + a3y*a3y + a3z*a3z) + EPSF;
    a3x /= n3; a3y /= n3; a3z /= n3;

    float den = vn + EPSF;
    float f1 = (pcx*a1x + pcy*a1y + pcz*a1z) / den;
    float f2 = (pcx*a2x + pcy*a2y + pcz*a2z) / den;
    float f3 = (pcx*a3x + pcy*a3y + pcz*a3z) / den;
    feat_up[q*64 + lane] = make_float4(f1, f2, f3, vn);
}

// ---------------- 5-layer MLP via bf16 MFMA + max over K ----------------
// One wave per point. Y^T = W^T * X^T so C/D layout (row=out-feat, col=neighbor)
// re-packs into next layer's B layout (B_lds[n=neighbor][k=feat]) with b64 writes.
// A = gwT[o][i] bf16 from global (L1-resident, 8KB/layer). Layer0 zero-padded K=32.
#define BROW 72   // ushorts per B_lds row (64 data + 8 pad); 144 B, 16B-aligned
__global__ __launch_bounds__(256) void mlp_kernel(
    const float4* __restrict__ feat_up,
    const unsigned short* __restrict__ gwt,
    float* __restrict__ embup)
{
    __shared__ __align__(16) unsigned short Blds[4][64 * BROW];
    const int lane = threadIdx.x & 63;
    const int wid  = threadIdx.x >> 6;
    const int q = blockIdx.x * 4 + wid;
    const int c = lane & 15, g = lane >> 4;
    unsigned short* B = Blds[wid];

    // stage B0: B[n=neighbor][k=0..3] = feats, k=4..31 zero
    {
        float4 f = feat_up[q*64 + lane];
        uint2 p0;
        p0.x = (unsigned)f2bf(f.x) | ((unsigned)f2bf(f.y) << 16);
        p0.y = (unsigned)f2bf(f.z) | ((unsigned)f2bf(f.w) << 16);
        *(uint2*)&B[lane*BROW] = p0;
        *(uint2*)&B[lane*BROW + 4] = make_uint2(0, 0);
        uint4 z4 = make_uint4(0, 0, 0, 0);
        *(uint4*)&B[lane*BROW + 8]  = z4;
        *(uint4*)&B[lane*BROW + 16] = z4;
        *(uint4*)&B[lane*BROW + 24] = z4;
    }

    const unsigned short* Wl[5] = {gwt, gwt + 2048, gwt + 6144, gwt + 10240, gwt + 14336};
    f32x4 acc[4][4];

    for (int layer = 0; layer < 5; ++layer) {
        const int wstride = (layer == 0) ? 32 : 64;
        const int nks = (layer == 0) ? 1 : 2;
        #pragma unroll
        for (int mb = 0; mb < 4; ++mb)
            #pragma unroll
            for (int nb = 0; nb < 4; ++nb)
                acc[mb][nb] = (f32x4){0.f, 0.f, 0.f, 0.f};

        for (int ks = 0; ks < nks; ++ks) {
            bf16x8 af[4], bf[4];
            #pragma unroll
            for (int mb = 0; mb < 4; ++mb)
                af[mb] = *(const bf16x8*)(Wl[layer] + (mb*16 + c)*wstride + ks*32 + g*8);
            #pragma unroll
            for (int nb = 0; nb < 4; ++nb)
                bf[nb] = *(const bf16x8*)&B[(nb*16 + c)*BROW + ks*32 + g*8];
            #pragma unroll
            for (int mb = 0; mb < 4; ++mb)
                #pragma unroll
                for (int nb = 0; nb < 4; ++nb)
                    acc[mb][nb] = __builtin_amdgcn_mfma_f32_16x16x32_bf16(af[mb], bf[nb], acc[mb][nb], 0, 0, 0);
        }

        if (layer < 4) {
            // ReLU + pack to bf16 + store into B layout for next layer
            #pragma unroll
            for (int mb = 0; mb < 4; ++mb) {
                #pragma unroll
                for (int nb = 0; nb < 4; ++nb) {
                    f32x4 a = acc[mb][nb];
                    float r0 = fmaxf(a[0], 0.f), r1 = fmaxf(a[1], 0.f);
                    float r2 = fmaxf(a[2], 0.f), r3 = fmaxf(a[3], 0.f);
                    uint2 pw;
                    pw.x = (unsigned)f2bf(r0) | ((unsigned)f2bf(r1) << 16);
                    pw.y = (unsigned)f2bf(r2) | ((unsigned)f2bf(r3) << 16);
                    *(uint2*)&B[(nb*16 + c)*BROW + mb*16 + g*4] = pw;
                }
            }
        }
    }

    // epilogue: ReLU + max over neighbors (cols); rows m = mb*16 + g*4 + r
    #pragma unroll
    for (int mb = 0; mb < 4; ++mb) {
        float v[4];
        #pragma unroll
        for (int r = 0; r < 4; ++r)
            v[r] = fmaxf(fmaxf(fmaxf(acc[mb][0][r], acc[mb][1][r]),
                               fmaxf(acc[mb][2][r], acc[mb][3][r])), 0.f);
        #pragma unroll
        for (int mask = 1; mask <= 8; mask <<= 1)
            #pragma unroll
            for (int r = 0; r < 4; ++r)
                v[r] = fmaxf(v[r], __shfl_xor(v[r], mask));
        if (c == 0)
            *(float4*)&embup[q*64 + mb*16 + g*4] = make_float4(v[0], v[1], v[2], v[3]);
    }
}

// ---------------- conv1x1 : y[o][p] = b[o] + sum_c WT[c][o] * x[c][p] ----------------
__global__ __launch_bounds__(256) void conv_kernel(
    const float* __restrict__ x, const float* __restrict__ wt,
    const float* __restrict__ bias, float* __restrict__ y, int C, int O)
{
    int p  = blockIdx.x * 256 + threadIdx.x;
    int o0 = blockIdx.y * 32;
    float acc[32];
    #pragma unroll
    for (int u = 0; u < 32; ++u) acc[u] = bias[o0 + u];
    for (int c = 0; c < C; ++c) {
        float xv = x[c * NPTS + p];
        const float* wr = wt + c * O + o0;
        #pragma unroll
        for (int u = 0; u < 32; ++u) acc[u] = fmaf(xv, wr[u], acc[u]);
    }
    #pragma unroll
    for (int u = 0; u < 32; ++u) y[(o0 + u) * NPTS + p] = acc[u];
}

// ---------------- per-channel sum / sumsq ----------------
__global__ __launch_bounds__(256) void stats_kernel(
    const float* __restrict__ y, float* __restrict__ st)
{
    int c = blockIdx.x;
    float s = 0.f, ss = 0.f;
    for (int t = threadIdx.x; t < NPTS; t += 256) {
        float v = y[c * NPTS + t];
        s += v; ss += v * v;
    }
    for (int j = 32; j > 0; j >>= 1) { s += __shfl_xor(s, j); ss += __shfl_xor(ss, j); }
    __shared__ float ls[4], lss[4];
    int wid = threadIdx.x >> 6;
    if ((threadIdx.x & 63) == 0) { ls[wid] = s; lss[wid] = ss; }
    __syncthreads();
    if (threadIdx.x == 0) {
        float S  = ls[0]+ls[1]+ls[2]+ls[3];
        float SS = lss[0]+lss[1]+lss[2]+lss[3];
        st[c] = S;
        st[gridDim.x + c] = SS;
    }
}

// ---------------- BN (training batch stats) + ReLU ----------------
__global__ __launch_bounds__(256) void bnrelu_kernel(
    const float* y, const float* __restrict__ st,
    const float* __restrict__ g, const float* __restrict__ b,
    float* out, int C)
{
    int idx = blockIdx.x * 256 + threadIdx.x;
    int c = idx >> 13;   // N = 8192
    float mu  = st[c] * (1.f / 8192.f);
    float var = st[C + c] * (1.f / 8192.f) - mu * mu;
    float scale = g[c] / sqrtf(var + 1e-5f);
    float v = fmaf(y[idx] - mu, scale, b[c]);
    out[idx] = fmaxf(v, 0.f);
}

extern "C" void kernel_launch(void* const* d_in, const int* in_sizes, int n_in,
                              void* d_out, int out_size, void* d_ws, size_t ws_size,
                              hipStream_t stream) {
    const float* points = (const float*)d_in[0];
    const float* gw0 = (const float*)d_in[1];
    const float* gw1 = (const float*)d_in[2];
    const float* gw2 = (const float*)d_in[3];
    const float* gw3 = (const float*)d_in[4];
    const float* gw4 = (const float*)d_in[5];
    const float* c1w = (const float*)d_in[6];  const float* c1b = (const float*)d_in[7];
    const float* bn1g = (const float*)d_in[8]; const float* bn1b = (const float*)d_in[9];
    const float* c2w = (const float*)d_in[10]; const float* c2b = (const float*)d_in[11];
    const float* bn2g = (const float*)d_in[12];const float* bn2b = (const float*)d_in[13];
    const float* c3w = (const float*)d_in[14]; const float* c3b = (const float*)d_in[15];
    const float* bn3g = (const float*)d_in[16];const float* bn3b = (const float*)d_in[17];
    const float* c4w = (const float*)d_in[18]; const float* c4b = (const float*)d_in[19];
    const float* bn4g = (const float*)d_in[20];const float* bn4b = (const float*)d_in[21];

    float* ws = (float*)d_ws;
    float* px = ws + OFF_PX; float* py = ws + OFF_PY;
    float* pz = ws + OFF_PZ; float* pr = ws + OFF_R;
    float* featdn = ws + OFF_FEATDN;
    float* featup = ws + OFF_FEATUP;
    float* embup  = ws + OFF_EMB;
    float* emb    = ws + OFF_EMB;
    float* h1 = ws + OFF_H1;
    float* h2 = ws + OFF_EMB + 64 * NPTS;
    float* h3 = ws + OFF_FEATUP;
    float* y1 = ws + OFF_Y1; float* y2 = ws + OFF_Y2; float* y3 = ws + OFF_Y3;
    float* s1 = ws + OFF_STATS + 0;
    float* s2 = ws + OFF_STATS + 128;
    float* s3 = ws + OFF_STATS + 384;
    float* s4 = ws + OFF_STATS + 896;
    float* wt1 = ws + OFF_WT1; float* wt2 = ws + OFF_WT2;
    float* wt3 = ws + OFF_WT3; float* wt4 = ws + OFF_WT4;
    const unsigned short* gwt = (const unsigned short*)(ws + OFF_Y3);
    float* outp = (float*)d_out;

    prep_a_kernel<<<32, 256, 0, stream>>>(points, ws);
    prep_b_kernel<<<1, 64, 0, stream>>>(points, ws);
    prep_c_kernel<<<32, 256, 0, stream>>>(ws);
    wt_kernel<<<256, 256, 0, stream>>>(c1w, c2w, c3w, c4w, gw0, gw1, gw2, gw3, gw4, ws);

    knn_feat_kernel<<<512, 1024, 0, stream>>>(px, py, pz, pr, (float4*)featup);
    mlp_kernel<<<2048, 256, 0, stream>>>((const float4*)featup, gwt, embup);

    conv_kernel<<<dim3(32, 2), 256, 0, stream>>>(featdn, wt1, c1b, y1, 4, 64);
    stats_kernel<<<64, 256, 0, stream>>>(y1, s1);
    bnrelu_kernel<<<64*32, 256, 0, stream>>>(y1, s1, bn1g, bn1b, h1, 64);

    conv_kernel<<<dim3(32, 4), 256, 0, stream>>>(h1, wt2, c2b, y2, 64, 128);
    stats_kernel<<<128, 256, 0, stream>>>(y2, s2);
    bnrelu_kernel<<<128*32, 256, 0, stream>>>(y2, s2, bn2g, bn2b, h2, 128);

    conv_kernel<<<dim3(32, 8), 256, 0, stream>>>(emb, wt3, c3b, y3, 192, 256);
    stats_kernel<<<256, 256, 0, stream>>>(y3, s3);
    bnrelu_kernel<<<256*32, 256, 0, stream>>>(y3, s3, bn3g, bn3b, h3, 256);

    conv_kernel<<<dim3(32, 32), 256, 0, stream>>>(h3, wt4, c4b, outp, 256, 1024);
    stats_kernel<<<1024, 256, 0, stream>>>(outp, s4);
    bnrelu_kernel<<<1024*32, 256, 0, stream>>>(outp, s4, bn4g, bn4b, outp, 1024);
}

// Round 4
// 483.436 us; speedup vs baseline: 2.8838x; 1.0055x over previous
//
#include <hip/hip_runtime.h>
#include <hip/hip_bf16.h>

#define NPTS 8192
#define KNN 64
#define EPSF 1e-7f

// ---------------- workspace layout (float offsets) ----------------
#define OFF_P4      0              // packed (x,y,z,rr) float4 per point: 4*N
#define OFF_STATS   32768          // s1:+0(128) s2:+128(256) s3:+384(512) s4:+896(2048) = 2944 total
#define OFF_AVEC    36000          // 9 floats a1,a2,a3
#define OFF_PART    36012          // 32 blocks x 2 u64 = 128 floats
#define OFF_FEATDN  36864          // N*4
#define OFF_EMB     69632          // embup 64*N (raw flat [n][64] == channel view [64][n])
#define OFF_Y1      2166784        // 64*N
#define OFF_Y2      2691072        // 128*N
#define OFF_Y3      3739648        // 256*N ; gwT bf16 parked here until conv3 writes y3
#define OFF_FEATUP  5836800        // N*K*4
#define OFF_WT1     7933952        // 4*64
#define OFF_WT2     7934208        // 64*128
#define OFF_WT3     7942400        // 192*256
#define OFF_WT4     7991552        // 256*1024

typedef __bf16 bf16x8 __attribute__((ext_vector_type(8)));
typedef float  f32x4  __attribute__((ext_vector_type(4)));

__device__ __forceinline__ unsigned f2u(float f) {
    unsigned u = __float_as_uint(f);
    return ((int)u >= 0) ? (u | 0x80000000u) : ~u;
}
__device__ __forceinline__ float key_to_f(unsigned long long k) {
    unsigned v = (unsigned)(k >> 32);
    unsigned ob = (v & 0x80000000u) ? (v ^ 0x80000000u) : ~v;
    return __uint_as_float(ob);
}
__device__ __forceinline__ unsigned short f2bf(float x) {
    unsigned u = __float_as_uint(x);
    unsigned r = (u + 0x7FFFu + ((u >> 16) & 1u)) >> 16;   // RNE
    return (unsigned short)r;
}
__device__ __forceinline__ unsigned long long u64min(unsigned long long a, unsigned long long b){ return a < b ? a : b; }
__device__ __forceinline__ unsigned long long u64max(unsigned long long a, unsigned long long b){ return a < b ? b : a; }

// bitonic sort 64 keys ascending across lanes, then merge with cur (sorted asc),
// returning the 64 smallest (sorted asc).
__device__ __forceinline__ unsigned long long sort_merge(
    unsigned long long key, unsigned long long cur, int lane)
{
    #pragma unroll
    for (int k = 2; k <= 64; k <<= 1) {
        #pragma unroll
        for (int j = k >> 1; j > 0; j >>= 1) {
            unsigned long long o = __shfl_xor(key, j);
            bool up = ((lane & k) == 0);
            bool lower = ((lane & j) == 0);
            key = (lower == up) ? u64min(key, o) : u64max(key, o);
        }
    }
    unsigned long long rev = __shfl(key, 63 - lane);
    unsigned long long m = u64min(cur, rev);     // bitonic sequence
    #pragma unroll
    for (int j = 32; j > 0; j >>= 1) {
        unsigned long long o = __shfl_xor(m, j);
        m = ((lane & j) == 0) ? u64min(m, o) : u64max(m, o);
    }
    return m;
}

// ---------------- prep A: packed p4, per-block argmax/argmin partials ----------------
__global__ __launch_bounds__(256) void prep_a_kernel(
    const float* __restrict__ points, float* __restrict__ ws)
{
    const int n = blockIdx.x * 256 + threadIdx.x;
    float x = points[3*n+0], y = points[3*n+1], z = points[3*n+2];
    float rr = x*x + y*y + z*z;
    ((float4*)(ws + OFF_P4))[n] = make_float4(x, y, z, rr);
    float vn = sqrtf(rr);
    unsigned b = __float_as_uint(vn);
    unsigned long long mxk = ((unsigned long long)b << 32) | (unsigned long long)(0xFFFFFFFFu - (unsigned)n);
    unsigned long long mnk = ((unsigned long long)b << 32) | (unsigned long long)(unsigned)n;
    for (int j = 32; j > 0; j >>= 1) {
        mxk = u64max(mxk, __shfl_xor(mxk, j));
        mnk = u64min(mnk, __shfl_xor(mnk, j));
    }
    __shared__ unsigned long long smx[4], smn[4];
    int wid = threadIdx.x >> 6;
    if ((threadIdx.x & 63) == 0) { smx[wid] = mxk; smn[wid] = mnk; }
    __syncthreads();
    if (threadIdx.x == 0) {
        unsigned long long MX = 0ull, MN = ~0ull;
        for (int i = 0; i < 4; ++i) { MX = u64max(MX, smx[i]); MN = u64min(MN, smn[i]); }
        unsigned long long* parts = (unsigned long long*)(ws + OFF_PART);
        parts[2*blockIdx.x + 0] = MX;
        parts[2*blockIdx.x + 1] = MN;
    }
}

// ---------------- prep B: reduce partials, compute a1/a2/a3 ----------------
__global__ __launch_bounds__(64) void prep_b_kernel(
    const float* __restrict__ points, float* __restrict__ ws)
{
    const int lane = threadIdx.x;
    const unsigned long long* parts = (const unsigned long long*)(ws + OFF_PART);
    unsigned long long mxk = (lane < 32) ? parts[2*lane + 0] : 0ull;
    unsigned long long mnk = (lane < 32) ? parts[2*lane + 1] : ~0ull;
    for (int j = 32; j > 0; j >>= 1) {
        mxk = u64max(mxk, __shfl_xor(mxk, j));
        mnk = u64min(mnk, __shfl_xor(mnk, j));
    }
    if (lane == 0) {
        int i1 = (int)(0xFFFFFFFFu - (unsigned)(mxk & 0xFFFFFFFFu));
        int i2 = (int)(unsigned)(mnk & 0xFFFFFFFFu);
        float a1x = points[3*i1+0], a1y = points[3*i1+1], a1z = points[3*i1+2];
        float n1 = sqrtf(a1x*a1x + a1y*a1y + a1z*a1z) + EPSF;
        a1x /= n1; a1y /= n1; a1z /= n1;
        float a2x = points[3*i2+0], a2y = points[3*i2+1], a2z = points[3*i2+2];
        float n2 = sqrtf(a2x*a2x + a2y*a2y + a2z*a2z) + EPSF;
        a2x /= n2; a2y /= n2; a2z /= n2;
        float a3x = a1x + 1.5f*a2x, a3y = a1y + 1.5f*a2y, a3z = a1z + 1.5f*a2z;
        float n3 = sqrtf(a3x*a3x + a3y*a3y + a3z*a3z) + EPSF;
        a3x /= n3; a3y /= n3; a3z /= n3;
        float* av = ws + OFF_AVEC;
        av[0]=a1x; av[1]=a1y; av[2]=a1z;
        av[3]=a2x; av[4]=a2y; av[5]=a2z;
        av[6]=a3x; av[7]=a3y; av[8]=a3z;
    }
}

// ---------------- prep C: feat_down ----------------
__global__ __launch_bounds__(256) void prep_c_kernel(float* __restrict__ ws)
{
    const int n = blockIdx.x * 256 + threadIdx.x;
    const float* av = ws + OFF_AVEC;
    float4 v = ((const float4*)(ws + OFF_P4))[n];
    float vn = sqrtf(v.w);
    float den = vn + EPSF;
    float f1 = (v.x*av[0] + v.y*av[1] + v.z*av[2]) / den;
    float f2 = (v.x*av[3] + v.y*av[4] + v.z*av[5]) / den;
    float f3 = (v.x*av[6] + v.y*av[7] + v.z*av[8]) / den;
    float4* f4 = (float4*)(ws + OFF_FEATDN + 4*n);
    *f4 = make_float4(f1, f2, f3, vn);
}

// ---------------- weight transposes + bf16 MLP weights + stats zero ----------------
// blocks 0..63: tiled transpose of c4w (1024x256 -> 256x1024). blocks 64..255: rest.
__global__ __launch_bounds__(256) void wt_kernel(
    const float* __restrict__ c1w, const float* __restrict__ c2w,
    const float* __restrict__ c3w, const float* __restrict__ c4w,
    const float* __restrict__ gw0, const float* __restrict__ gw1,
    const float* __restrict__ gw2, const float* __restrict__ gw3,
    const float* __restrict__ gw4,
    float* __restrict__ ws)
{
    {   // zero stats accumulators (all blocks write 0 — benign duplicate)
        const int t = blockIdx.x * 256 + threadIdx.x;
        const int T = gridDim.x * 256;
        for (int m = t; m < 2944; m += T) ws[OFF_STATS + m] = 0.f;
    }
    if (blockIdx.x < 64) {
        __shared__ float tile[64][65];
        int bo = (blockIdx.x & 15) * 64;   // o-tile (1024/64 = 16)
        int bc = (blockIdx.x >> 4) * 64;   // c-tile (256/64 = 4)
        int tx = threadIdx.x & 63, ty = threadIdx.x >> 6;
        for (int r = ty; r < 64; r += 4) tile[r][tx] = c4w[(bo + r)*256 + bc + tx];
        __syncthreads();
        for (int r = ty; r < 64; r += 4) ws[OFF_WT4 + (bc + r)*1024 + bo + tx] = tile[tx][r];
        return;
    }
    const int t = (blockIdx.x - 64) * 256 + threadIdx.x;
    const int T = (gridDim.x - 64) * 256;
    for (int m = t; m < 64*4; m += T)    { int o = m >> 2, c = m & 3;       ws[OFF_WT1 + c*64   + o] = c1w[m]; }
    for (int m = t; m < 128*64; m += T)  { int o = m >> 6, c = m & 63;      ws[OFF_WT2 + c*128  + o] = c2w[m]; }
    for (int m = t; m < 256*192; m += T) { int o = m / 192, c = m - o*192;  ws[OFF_WT3 + c*256  + o] = c3w[m]; }

    unsigned short* gwt = (unsigned short*)(ws + OFF_Y3);
    for (int m = t; m < 2048; m += T) {          // gw0T padded [64][32]
        int o = m >> 5, i = m & 31;
        gwt[m] = (i < 4) ? f2bf(gw0[i*64 + o]) : (unsigned short)0;
    }
    const float* gsrc[4] = {gw1, gw2, gw3, gw4};
    for (int l = 0; l < 4; ++l) {
        const float* g = gsrc[l];
        unsigned short* dst = gwt + 2048 + l*4096;
        for (int m = t; m < 4096; m += T) { int o = m >> 6, i = m & 63; dst[m] = f2bf(g[i*64 + o]); }
    }
}

// ---------------- KNN + local rotation-invariant features ----------------
// 512 blocks x 512 threads (8 waves); each wave handles 2 queries.
// Packed float4 candidates in LDS (1 ds_read_b128/iter), float-distance filter,
// LDS candidate queue, bitonic sort+merge only when 64 accumulated.
__global__ __launch_bounds__(512) void knn_feat_kernel(
    const float4* __restrict__ p4, float4* __restrict__ feat_up)
{
    __shared__ __align__(16) float4 scand[2048];                 // 32 KB
    __shared__ unsigned long long queue[8][2][128];              // 16 KB
    const int lane = threadIdx.x & 63;
    const int wid  = threadIdx.x >> 6;
    const int q0 = blockIdx.x * 16 + wid * 2;

    const float4 qa = p4[q0];
    const float4 qb = p4[q0 + 1];
    unsigned long long cur0 = ~0ull, cur1 = ~0ull;
    float kthd0 = __builtin_inff(), kthd1 = __builtin_inff();
    int qc0 = 0, qc1 = 0;
    unsigned long long* Q0 = queue[wid][0];
    unsigned long long* Q1 = queue[wid][1];

    for (int base = 0; base < NPTS; base += 2048) {
        __syncthreads();
        for (int t = threadIdx.x; t < 2048; t += 512) scand[t] = p4[base + t];
        __syncthreads();
        #pragma unroll 2
        for (int sub = 0; sub < 2048; sub += 64) {
            float4 cd = scand[sub + lane];
            float dot0 = fmaf(qa.x, cd.x, fmaf(qa.y, cd.y, qa.z * cd.z));
            float d0   = fmaf(-2.f, dot0, qa.w) + cd.w;
            float dot1 = fmaf(qb.x, cd.x, fmaf(qb.y, cd.y, qb.z * cd.z));
            float d1   = fmaf(-2.f, dot1, qb.w) + cd.w;
            bool p0 = d0 < kthd0, p1 = d1 < kthd1;
            unsigned long long m0 = __ballot(p0);
            unsigned long long m1 = __ballot(p1);
            if (m0) {
                int prefix = __builtin_amdgcn_mbcnt_hi((unsigned)(m0 >> 32),
                              __builtin_amdgcn_mbcnt_lo((unsigned)m0, 0));
                if (p0) Q0[qc0 + prefix] = ((unsigned long long)f2u(d0) << 32)
                                         | (unsigned long long)(unsigned)(base + sub + lane);
                qc0 += __popcll(m0);
                if (qc0 >= 64) {
                    qc0 -= 64;
                    cur0 = sort_merge(Q0[qc0 + lane], cur0, lane);
                    kthd0 = key_to_f(__shfl(cur0, 63));
                }
            }
            if (m1) {
                int prefix = __builtin_amdgcn_mbcnt_hi((unsigned)(m1 >> 32),
                              __builtin_amdgcn_mbcnt_lo((unsigned)m1, 0));
                if (p1) Q1[qc1 + prefix] = ((unsigned long long)f2u(d1) << 32)
                                         | (unsigned long long)(unsigned)(base + sub + lane);
                qc1 += __popcll(m1);
                if (qc1 >= 64) {
                    qc1 -= 64;
                    cur1 = sort_merge(Q1[qc1 + lane], cur1, lane);
                    kthd1 = key_to_f(__shfl(cur1, 63));
                }
            }
        }
    }
    cur0 = sort_merge((lane < qc0) ? Q0[lane] : ~0ull, cur0, lane);
    cur1 = sort_merge((lane < qc1) ? Q1[lane] : ~0ull, cur1, lane);

    // features for both queries; lane k = k-th nearest (asc distance, idx tie-break)
    #pragma unroll 1
    for (int j = 0; j < 2; ++j) {
        unsigned long long cur = j ? cur1 : cur0;
        const int q = q0 + j;
        int nidx = (int)(unsigned)(cur & 0xFFFFFFFFu);
        float4 np = p4[nidx];
        float ox = __shfl(np.x, 0), oy = __shfl(np.y, 0), oz = __shfl(np.z, 0);
        float pcx = np.x - ox, pcy = np.y - oy, pcz = np.z - oz;
        float vn = sqrtf(pcx*pcx + pcy*pcy + pcz*pcz);

        unsigned long long ak = ((unsigned long long)__float_as_uint(vn) << 32)
                              | (unsigned long long)(unsigned)(63 - lane);
        for (int s = 32; s > 0; s >>= 1) ak = u64max(ak, __shfl_xor(ak, s));
        int id1 = 63 - (int)(unsigned)(ak & 0xFFFFFFFFu);

        float a1x = __shfl(pcx, id1), a1y = __shfl(pcy, id1), a1z = __shfl(pcz, id1);
        float n1 = sqrtf(a1x*a1x + a1y*a1y + a1z*a1z) + EPSF;
        a1x /= n1; a1y /= n1; a1z /= n1;

        float sx = pcx, sy = pcy, sz = pcz;
        for (int s = 32; s > 0; s >>= 1) {
            sx += __shfl_xor(sx, s); sy += __shfl_xor(sy, s); sz += __shfl_xor(sz, s);
        }
        float a2x = sx * (1.f/64.f), a2y = sy * (1.f/64.f), a2z = sz * (1.f/64.f);
        float n2 = sqrtf(a2x*a2x + a2y*a2y + a2z*a2z) + EPSF;
        a2x /= n2; a2y /= n2; a2z /= n2;

        float a3x = a1x + 1.5f*a2x, a3y = a1y + 1.5f*a2y, a3z = a1z + 1.5f*a2z;
        float n3 = sqrtf(a3x*a3x + a3y*a3y + a3z*a3z) + EPSF;
        a3x /= n3; a3y /= n3; a3z /= n3;

        float den = vn + EPSF;
        float f1 = (pcx*a1x + pcy*a1y + pcz*a1z) / den;
        float f2 = (pcx*a2x + pcy*a2y + pcz*a2z) / den;
        float f3 = (pcx*a3x + pcy*a3y + pcz*a3z) / den;
        feat_up[q*64 + lane] = make_float4(f1, f2, f3, vn);
    }
}

// ---------------- 5-layer MLP via bf16 MFMA + max over K ----------------
#define BROW 72
__global__ __launch_bounds__(256) void mlp_kernel(
    const float4* __restrict__ feat_up,
    const unsigned short* __restrict__ gwt,
    float* __restrict__ embup)
{
    __shared__ __align__(16) unsigned short Blds[4][64 * BROW];
    const int lane = threadIdx.x & 63;
    const int wid  = threadIdx.x >> 6;
    const int q = blockIdx.x * 4 + wid;
    const int c = lane & 15, g = lane >> 4;
    unsigned short* B = Blds[wid];

    {
        float4 f = feat_up[q*64 + lane];
        uint2 p0;
        p0.x = (unsigned)f2bf(f.x) | ((unsigned)f2bf(f.y) << 16);
        p0.y = (unsigned)f2bf(f.z) | ((unsigned)f2bf(f.w) << 16);
        *(uint2*)&B[lane*BROW] = p0;
        *(uint2*)&B[lane*BROW + 4] = make_uint2(0, 0);
        uint4 z4 = make_uint4(0, 0, 0, 0);
        *(uint4*)&B[lane*BROW + 8]  = z4;
        *(uint4*)&B[lane*BROW + 16] = z4;
        *(uint4*)&B[lane*BROW + 24] = z4;
    }

    const unsigned short* Wl[5] = {gwt, gwt + 2048, gwt + 6144, gwt + 10240, gwt + 14336};
    f32x4 acc[4][4];

    for (int layer = 0; layer < 5; ++layer) {
        const int wstride = (layer == 0) ? 32 : 64;
        const int nks = (layer == 0) ? 1 : 2;
        #pragma unroll
        for (int mb = 0; mb < 4; ++mb)
            #pragma unroll
            for (int nb = 0; nb < 4; ++nb)
                acc[mb][nb] = (f32x4){0.f, 0.f, 0.f, 0.f};

        for (int ks = 0; ks < nks; ++ks) {
            bf16x8 af[4], bf[4];
            #pragma unroll
            for (int mb = 0; mb < 4; ++mb)
                af[mb] = *(const bf16x8*)(Wl[layer] + (mb*16 + c)*wstride + ks*32 + g*8);
            #pragma unroll
            for (int nb = 0; nb < 4; ++nb)
                bf[nb] = *(const bf16x8*)&B[(nb*16 + c)*BROW + ks*32 + g*8];
            #pragma unroll
            for (int mb = 0; mb < 4; ++mb)
                #pragma unroll
                for (int nb = 0; nb < 4; ++nb)
                    acc[mb][nb] = __builtin_amdgcn_mfma_f32_16x16x32_bf16(af[mb], bf[nb], acc[mb][nb], 0, 0, 0);
        }

        if (layer < 4) {
            #pragma unroll
            for (int mb = 0; mb < 4; ++mb) {
                #pragma unroll
                for (int nb = 0; nb < 4; ++nb) {
                    f32x4 a = acc[mb][nb];
                    float r0 = fmaxf(a[0], 0.f), r1 = fmaxf(a[1], 0.f);
                    float r2 = fmaxf(a[2], 0.f), r3 = fmaxf(a[3], 0.f);
                    uint2 pw;
                    pw.x = (unsigned)f2bf(r0) | ((unsigned)f2bf(r1) << 16);
                    pw.y = (unsigned)f2bf(r2) | ((unsigned)f2bf(r3) << 16);
                    *(uint2*)&B[(nb*16 + c)*BROW + mb*16 + g*4] = pw;
                }
            }
        }
    }

    #pragma unroll
    for (int mb = 0; mb < 4; ++mb) {
        float v[4];
        #pragma unroll
        for (int r = 0; r < 4; ++r)
            v[r] = fmaxf(fmaxf(fmaxf(acc[mb][0][r], acc[mb][1][r]),
                               fmaxf(acc[mb][2][r], acc[mb][3][r])), 0.f);
        #pragma unroll
        for (int mask = 1; mask <= 8; mask <<= 1)
            #pragma unroll
            for (int r = 0; r < 4; ++r)
                v[r] = fmaxf(v[r], __shfl_xor(v[r], mask));
        if (c == 0)
            *(float4*)&embup[q*64 + mb*16 + g*4] = make_float4(v[0], v[1], v[2], v[3]);
    }
}

// ---------------- fused conv1x1: [input-BN+ReLU on x1 channels] + GEMV + output stats ----------------
// y[o][p] = bias[o] + sum_{c<split} wt[c][o]*x0[c][p]
//                   + sum_{c>=split} wt[c][o]*relu(bn(x1[c-split][p]))
// Output per-channel sum/sumsq accumulated into stout via atomics (pre-zeroed).
__global__ __launch_bounds__(256) void conv_kernel(
    const float* __restrict__ x0, const float* __restrict__ x1,
    const float* __restrict__ stin, const float* __restrict__ gin,
    const float* __restrict__ bin, int split, int C, int O,
    const float* __restrict__ wt, const float* __restrict__ bias,
    float* __restrict__ y, float* __restrict__ stout)
{
    __shared__ float sc[256], sh[256];
    const int tid = threadIdx.x;
    const int nbn = C - split;
    for (int c = tid; c < nbn; c += 256) {
        float mu  = stin[c] * (1.f / 8192.f);
        float var = stin[nbn + c] * (1.f / 8192.f) - mu * mu;
        float s = gin[c] / sqrtf(var + 1e-5f);
        sc[c] = s; sh[c] = bin[c] - mu * s;
    }
    __syncthreads();

    const int p  = blockIdx.x * 256 + tid;
    const int o0 = blockIdx.y * 32;
    float acc[32];
    #pragma unroll
    for (int u = 0; u < 32; ++u) acc[u] = bias[o0 + u];
    for (int c = 0; c < split; ++c) {
        float xv = x0[c * NPTS + p];
        const float* wr = wt + c * O + o0;
        #pragma unroll
        for (int u = 0; u < 32; ++u) acc[u] = fmaf(xv, wr[u], acc[u]);
    }
    for (int c = 0; c < nbn; ++c) {
        float xv = x1[c * NPTS + p];
        xv = fmaxf(fmaf(xv, sc[c], sh[c]), 0.f);
        const float* wr = wt + (split + c) * O + o0;
        #pragma unroll
        for (int u = 0; u < 32; ++u) acc[u] = fmaf(xv, wr[u], acc[u]);
    }
    #pragma unroll
    for (int u = 0; u < 32; ++u) y[(o0 + u) * NPTS + p] = acc[u];

    // output stats: reduce across the block's 256 positions, one atomic pair per channel
    __shared__ float ps[4][32], pss[4][32];
    const int wid = tid >> 6, lane = tid & 63;
    #pragma unroll
    for (int u = 0; u < 32; ++u) {
        float s = acc[u], ss = acc[u] * acc[u];
        for (int j = 32; j > 0; j >>= 1) { s += __shfl_xor(s, j); ss += __shfl_xor(ss, j); }
        if (lane == 0) { ps[wid][u] = s; pss[wid][u] = ss; }
    }
    __syncthreads();
    if (tid < 32) {
        float S  = ps[0][tid] + ps[1][tid] + ps[2][tid] + ps[3][tid];
        float SS = pss[0][tid] + pss[1][tid] + pss[2][tid] + pss[3][tid];
        atomicAdd(&stout[o0 + tid], S);
        atomicAdd(&stout[O + o0 + tid], SS);
    }
}

// ---------------- final BN + ReLU (in place on d_out) ----------------
__global__ __launch_bounds__(256) void bnrelu_kernel(
    const float* y, const float* __restrict__ st,
    const float* __restrict__ g, const float* __restrict__ b,
    float* out, int C)
{
    int idx = blockIdx.x * 256 + threadIdx.x;
    int c = idx >> 13;   // N = 8192
    float mu  = st[c] * (1.f / 8192.f);
    float var = st[C + c] * (1.f / 8192.f) - mu * mu;
    float scale = g[c] / sqrtf(var + 1e-5f);
    float v = fmaf(y[idx] - mu, scale, b[c]);
    out[idx] = fmaxf(v, 0.f);
}

extern "C" void kernel_launch(void* const* d_in, const int* in_sizes, int n_in,
                              void* d_out, int out_size, void* d_ws, size_t ws_size,
                              hipStream_t stream) {
    const float* points = (const float*)d_in[0];
    const float* gw0 = (const float*)d_in[1];
    const float* gw1 = (const float*)d_in[2];
    const float* gw2 = (const float*)d_in[3];
    const float* gw3 = (const float*)d_in[4];
    const float* gw4 = (const float*)d_in[5];
    const float* c1w = (const float*)d_in[6];  const float* c1b = (const float*)d_in[7];
    const float* bn1g = (const float*)d_in[8]; const float* bn1b = (const float*)d_in[9];
    const float* c2w = (const float*)d_in[10]; const float* c2b = (const float*)d_in[11];
    const float* bn2g = (const float*)d_in[12];const float* bn2b = (const float*)d_in[13];
    const float* c3w = (const float*)d_in[14]; const float* c3b = (const float*)d_in[15];
    const float* bn3g = (const float*)d_in[16];const float* bn3b = (const float*)d_in[17];
    const float* c4w = (const float*)d_in[18]; const float* c4b = (const float*)d_in[19];
    const float* bn4g = (const float*)d_in[20];const float* bn4b = (const float*)d_in[21];

    float* ws = (float*)d_ws;
    float* p4f    = ws + OFF_P4;
    float* featdn = ws + OFF_FEATDN;
    float* featup = ws + OFF_FEATUP;
    float* embup  = ws + OFF_EMB;
    float* y1 = ws + OFF_Y1; float* y2 = ws + OFF_Y2; float* y3 = ws + OFF_Y3;
    float* s1 = ws + OFF_STATS + 0;
    float* s2 = ws + OFF_STATS + 128;
    float* s3 = ws + OFF_STATS + 384;
    float* s4 = ws + OFF_STATS + 896;
    float* wt1 = ws + OFF_WT1; float* wt2 = ws + OFF_WT2;
    float* wt3 = ws + OFF_WT3; float* wt4 = ws + OFF_WT4;
    const unsigned short* gwt = (const unsigned short*)(ws + OFF_Y3);
    float* outp = (float*)d_out;

    prep_a_kernel<<<32, 256, 0, stream>>>(points, ws);
    prep_b_kernel<<<1, 64, 0, stream>>>(points, ws);
    prep_c_kernel<<<32, 256, 0, stream>>>(ws);
    wt_kernel<<<256, 256, 0, stream>>>(c1w, c2w, c3w, c4w, gw0, gw1, gw2, gw3, gw4, ws);

    knn_feat_kernel<<<512, 512, 0, stream>>>((const float4*)p4f, (float4*)featup);
    mlp_kernel<<<2048, 256, 0, stream>>>((const float4*)featup, gwt, embup);

    // conv1: 4 raw channels (featdn flat view), output stats -> s1
    conv_kernel<<<dim3(32, 2), 256, 0, stream>>>(featdn, featdn, s1, bn1g, bn1b,
                                                 4, 4, 64, wt1, c1b, y1, s1);
    // conv2: input = BN1(y1)+ReLU, output stats -> s2
    conv_kernel<<<dim3(32, 4), 256, 0, stream>>>(y1, y1, s1, bn1g, bn1b,
                                                 0, 64, 128, wt2, c2b, y2, s2);
    // conv3: ch 0..63 raw embup (flat view), ch 64..191 = BN2(y2)+ReLU, stats -> s3
    conv_kernel<<<dim3(32, 8), 256, 0, stream>>>(embup, y2, s2, bn2g, bn2b,
                                                 64, 192, 256, wt3, c3b, y3, s3);
    // conv4: input = BN3(y3)+ReLU, write pre-BN output to d_out, stats -> s4
    conv_kernel<<<dim3(32, 32), 256, 0, stream>>>(y3, y3, s3, bn3g, bn3b,
                                                  0, 256, 1024, wt4, c4b, outp, s4);
    // final BN4 + ReLU in place
    bnrelu_kernel<<<1024*32, 256, 0, stream>>>(outp, s4, bn4g, bn4b, outp, 1024);
}

// Round 6
// 370.766 us; speedup vs baseline: 3.7602x; 1.3039x over previous
//
#include <hip/hip_runtime.h>
#include <hip/hip_bf16.h>

#define NPTS 8192
#define KNN 64
#define EPSF 1e-7f

// ---------------- workspace layout (float offsets) ----------------
#define OFF_P4      0              // packed (x,y,z,rr) float4 per point: 4*N
#define OFF_STATS   32768          // s1:+0(128) s2:+128(256) s3:+384(512) s4:+896(2048) = 2944
#define OFF_AVEC    36000          // 9 floats a1,a2,a3
#define OFF_PART    36012          // 32 blocks x 2 u64 = 128 floats
#define OFF_FEATDN  36864          // N*4 -> 69632
#define OFF_WT1     69632          // 4*64 fp32 transposed -> 69888
#define OFF_GWT     69888          // MLP bf16 weights: 18432 shorts = 9216 -> 79104
#define OFF_BW2     79104          // c2w bf16: 8192 shorts = 4096 -> 83200
#define OFF_BW3     83200          // c3w bf16: 49152 shorts = 24576 -> 107776
#define OFF_BW4     107776         // c4w bf16: 262144 shorts = 131072 -> 238848
#define OFF_XB1     238848         // bf16 [8192][64]  = 262144 fl -> 500992
#define OFF_XB3     500992         // bf16 [8192][192] = 786432 fl -> 1287424
#define OFF_XB4     1287424        // bf16 [8192][256] = 1048576 fl -> 2336000
#define OFF_Y1      2336000        // 64*N fp32 -> 2860288
#define OFF_Y2      2860288        // 128*N fp32 -> 3908864
#define OFF_Y3      3908864        // 256*N fp32 -> 6006016
#define OFF_FEATUP  6006016        // N*K*4 fp32 -> 8103168 (~30.9 MB)

typedef __bf16 bf16x8 __attribute__((ext_vector_type(8)));
typedef float  f32x4  __attribute__((ext_vector_type(4)));

__device__ __forceinline__ unsigned f2u(float f) {
    unsigned u = __float_as_uint(f);
    return ((int)u >= 0) ? (u | 0x80000000u) : ~u;
}
__device__ __forceinline__ float key_to_f(unsigned long long k) {
    unsigned v = (unsigned)(k >> 32);
    unsigned ob = (v & 0x80000000u) ? (v ^ 0x80000000u) : ~v;
    return __uint_as_float(ob);
}
__device__ __forceinline__ unsigned short f2bf(float x) {
    unsigned u = __float_as_uint(x);
    unsigned r = (u + 0x7FFFu + ((u >> 16) & 1u)) >> 16;   // RNE
    return (unsigned short)r;
}
__device__ __forceinline__ unsigned long long u64min(unsigned long long a, unsigned long long b){ return a < b ? a : b; }
__device__ __forceinline__ unsigned long long u64max(unsigned long long a, unsigned long long b){ return a < b ? b : a; }

__device__ __forceinline__ unsigned long long sort_merge(
    unsigned long long key, unsigned long long cur, int lane)
{
    #pragma unroll
    for (int k = 2; k <= 64; k <<= 1) {
        #pragma unroll
        for (int j = k >> 1; j > 0; j >>= 1) {
            unsigned long long o = __shfl_xor(key, j);
            bool up = ((lane & k) == 0);
            bool lower = ((lane & j) == 0);
            key = (lower == up) ? u64min(key, o) : u64max(key, o);
        }
    }
    unsigned long long rev = __shfl(key, 63 - lane);
    unsigned long long m = u64min(cur, rev);
    #pragma unroll
    for (int j = 32; j > 0; j >>= 1) {
        unsigned long long o = __shfl_xor(m, j);
        m = ((lane & j) == 0) ? u64min(m, o) : u64max(m, o);
    }
    return m;
}

// ---------------- prep A ----------------
__global__ __launch_bounds__(256) void prep_a_kernel(
    const float* __restrict__ points, float* __restrict__ ws)
{
    const int n = blockIdx.x * 256 + threadIdx.x;
    float x = points[3*n+0], y = points[3*n+1], z = points[3*n+2];
    float rr = x*x + y*y + z*z;
    ((float4*)(ws + OFF_P4))[n] = make_float4(x, y, z, rr);
    float vn = sqrtf(rr);
    unsigned b = __float_as_uint(vn);
    unsigned long long mxk = ((unsigned long long)b << 32) | (unsigned long long)(0xFFFFFFFFu - (unsigned)n);
    unsigned long long mnk = ((unsigned long long)b << 32) | (unsigned long long)(unsigned)n;
    for (int j = 32; j > 0; j >>= 1) {
        mxk = u64max(mxk, __shfl_xor(mxk, j));
        mnk = u64min(mnk, __shfl_xor(mnk, j));
    }
    __shared__ unsigned long long smx[4], smn[4];
    int wid = threadIdx.x >> 6;
    if ((threadIdx.x & 63) == 0) { smx[wid] = mxk; smn[wid] = mnk; }
    __syncthreads();
    if (threadIdx.x == 0) {
        unsigned long long MX = 0ull, MN = ~0ull;
        for (int i = 0; i < 4; ++i) { MX = u64max(MX, smx[i]); MN = u64min(MN, smn[i]); }
        unsigned long long* parts = (unsigned long long*)(ws + OFF_PART);
        parts[2*blockIdx.x + 0] = MX;
        parts[2*blockIdx.x + 1] = MN;
    }
}

// ---------------- prep B ----------------
__global__ __launch_bounds__(64) void prep_b_kernel(
    const float* __restrict__ points, float* __restrict__ ws)
{
    const int lane = threadIdx.x;
    const unsigned long long* parts = (const unsigned long long*)(ws + OFF_PART);
    unsigned long long mxk = (lane < 32) ? parts[2*lane + 0] : 0ull;
    unsigned long long mnk = (lane < 32) ? parts[2*lane + 1] : ~0ull;
    for (int j = 32; j > 0; j >>= 1) {
        mxk = u64max(mxk, __shfl_xor(mxk, j));
        mnk = u64min(mnk, __shfl_xor(mnk, j));
    }
    if (lane == 0) {
        int i1 = (int)(0xFFFFFFFFu - (unsigned)(mxk & 0xFFFFFFFFu));
        int i2 = (int)(unsigned)(mnk & 0xFFFFFFFFu);
        float a1x = points[3*i1+0], a1y = points[3*i1+1], a1z = points[3*i1+2];
        float n1 = sqrtf(a1x*a1x + a1y*a1y + a1z*a1z) + EPSF;
        a1x /= n1; a1y /= n1; a1z /= n1;
        float a2x = points[3*i2+0], a2y = points[3*i2+1], a2z = points[3*i2+2];
        float n2 = sqrtf(a2x*a2x + a2y*a2y + a2z*a2z) + EPSF;
        a2x /= n2; a2y /= n2; a2z /= n2;
        float a3x = a1x + 1.5f*a2x, a3y = a1y + 1.5f*a2y, a3z = a1z + 1.5f*a2z;
        float n3 = sqrtf(a3x*a3x + a3y*a3y + a3z*a3z) + EPSF;
        a3x /= n3; a3y /= n3; a3z /= n3;
        float* av = ws + OFF_AVEC;
        av[0]=a1x; av[1]=a1y; av[2]=a1z;
        av[3]=a2x; av[4]=a2y; av[5]=a2z;
        av[6]=a3x; av[7]=a3y; av[8]=a3z;
    }
}

// ---------------- prep C: feat_down ----------------
__global__ __launch_bounds__(256) void prep_c_kernel(float* __restrict__ ws)
{
    const int n = blockIdx.x * 256 + threadIdx.x;
    const float* av = ws + OFF_AVEC;
    float4 v = ((const float4*)(ws + OFF_P4))[n];
    float vn = sqrtf(v.w);
    float den = vn + EPSF;
    float f1 = (v.x*av[0] + v.y*av[1] + v.z*av[2]) / den;
    float f2 = (v.x*av[3] + v.y*av[4] + v.z*av[5]) / den;
    float f3 = (v.x*av[6] + v.y*av[7] + v.z*av[8]) / den;
    float4* f4 = (float4*)(ws + OFF_FEATDN + 4*n);
    *f4 = make_float4(f1, f2, f3, vn);
}

// ---------------- weight prep: stats zero, wt1 transpose, bf16 conv+MLP weights ----------------
__global__ __launch_bounds__(256) void wt_kernel(
    const float* __restrict__ c1w, const float* __restrict__ c2w,
    const float* __restrict__ c3w, const float* __restrict__ c4w,
    const float* __restrict__ gw0, const float* __restrict__ gw1,
    const float* __restrict__ gw2, const float* __restrict__ gw3,
    const float* __restrict__ gw4,
    float* __restrict__ ws)
{
    const int t = blockIdx.x * 256 + threadIdx.x;
    const int T = gridDim.x * 256;
    for (int m = t; m < 2944; m += T) ws[OFF_STATS + m] = 0.f;
    for (int m = t; m < 64*4; m += T) { int o = m >> 2, c = m & 3; ws[OFF_WT1 + c*64 + o] = c1w[m]; }

    unsigned short* bw2 = (unsigned short*)(ws + OFF_BW2);
    for (int m = t; m < 128*64; m += T)   bw2[m] = f2bf(c2w[m]);
    unsigned short* bw3 = (unsigned short*)(ws + OFF_BW3);
    for (int m = t; m < 256*192; m += T)  bw3[m] = f2bf(c3w[m]);
    unsigned short* bw4 = (unsigned short*)(ws + OFF_BW4);
    for (int m = t; m < 1024*256; m += T) bw4[m] = f2bf(c4w[m]);

    unsigned short* gwt = (unsigned short*)(ws + OFF_GWT);
    for (int m = t; m < 2048; m += T) {          // gw0T padded [64][32]
        int o = m >> 5, i = m & 31;
        gwt[m] = (i < 4) ? f2bf(gw0[i*64 + o]) : (unsigned short)0;
    }
    const float* gsrc[4] = {gw1, gw2, gw3, gw4};
    for (int l = 0; l < 4; ++l) {
        const float* g = gsrc[l];
        unsigned short* dst = gwt + 2048 + l*4096;
        for (int m = t; m < 4096; m += T) { int o = m >> 6, i = m & 63; dst[m] = f2bf(g[i*64 + o]); }
    }
}

// ---------------- KNN + local rotation-invariant features ----------------
__global__ __launch_bounds__(512) void knn_feat_kernel(
    const float4* __restrict__ p4, float4* __restrict__ feat_up)
{
    __shared__ __align__(16) float4 scand[2048];
    __shared__ unsigned long long queue[8][2][128];
    const int lane = threadIdx.x & 63;
    const int wid  = threadIdx.x >> 6;
    const int q0 = blockIdx.x * 16 + wid * 2;

    const float4 qa = p4[q0];
    const float4 qb = p4[q0 + 1];
    unsigned long long cur0 = ~0ull, cur1 = ~0ull;
    float kthd0 = __builtin_inff(), kthd1 = __builtin_inff();
    int qc0 = 0, qc1 = 0;
    unsigned long long* Q0 = queue[wid][0];
    unsigned long long* Q1 = queue[wid][1];

    for (int base = 0; base < NPTS; base += 2048) {
        __syncthreads();
        for (int t = threadIdx.x; t < 2048; t += 512) scand[t] = p4[base + t];
        __syncthreads();
        #pragma unroll 2
        for (int sub = 0; sub < 2048; sub += 64) {
            float4 cd = scand[sub + lane];
            float dot0 = fmaf(qa.x, cd.x, fmaf(qa.y, cd.y, qa.z * cd.z));
            float d0   = fmaf(-2.f, dot0, qa.w) + cd.w;
            float dot1 = fmaf(qb.x, cd.x, fmaf(qb.y, cd.y, qb.z * cd.z));
            float d1   = fmaf(-2.f, dot1, qb.w) + cd.w;
            bool p0 = d0 < kthd0, p1 = d1 < kthd1;
            unsigned long long m0 = __ballot(p0);
            unsigned long long m1 = __ballot(p1);
            if (m0) {
                int prefix = __builtin_amdgcn_mbcnt_hi((unsigned)(m0 >> 32),
                              __builtin_amdgcn_mbcnt_lo((unsigned)m0, 0));
                if (p0) Q0[qc0 + prefix] = ((unsigned long long)f2u(d0) << 32)
                                         | (unsigned long long)(unsigned)(base + sub + lane);
                qc0 += __popcll(m0);
                if (qc0 >= 64) {
                    qc0 -= 64;
                    cur0 = sort_merge(Q0[qc0 + lane], cur0, lane);
                    kthd0 = key_to_f(__shfl(cur0, 63));
                }
            }
            if (m1) {
                int prefix = __builtin_amdgcn_mbcnt_hi((unsigned)(m1 >> 32),
                              __builtin_amdgcn_mbcnt_lo((unsigned)m1, 0));
                if (p1) Q1[qc1 + prefix] = ((unsigned long long)f2u(d1) << 32)
                                         | (unsigned long long)(unsigned)(base + sub + lane);
                qc1 += __popcll(m1);
                if (qc1 >= 64) {
                    qc1 -= 64;
                    cur1 = sort_merge(Q1[qc1 + lane], cur1, lane);
                    kthd1 = key_to_f(__shfl(cur1, 63));
                }
            }
        }
    }
    cur0 = sort_merge((lane < qc0) ? Q0[lane] : ~0ull, cur0, lane);
    cur1 = sort_merge((lane < qc1) ? Q1[lane] : ~0ull, cur1, lane);

    #pragma unroll 1
    for (int j = 0; j < 2; ++j) {
        unsigned long long cur = j ? cur1 : cur0;
        const int q = q0 + j;
        int nidx = (int)(unsigned)(cur & 0xFFFFFFFFu);
        float4 np = p4[nidx];
        float ox = __shfl(np.x, 0), oy = __shfl(np.y, 0), oz = __shfl(np.z, 0);
        float pcx = np.x - ox, pcy = np.y - oy, pcz = np.z - oz;
        float vn = sqrtf(pcx*pcx + pcy*pcy + pcz*pcz);

        unsigned long long ak = ((unsigned long long)__float_as_uint(vn) << 32)
                              | (unsigned long long)(unsigned)(63 - lane);
        for (int s = 32; s > 0; s >>= 1) ak = u64max(ak, __shfl_xor(ak, s));
        int id1 = 63 - (int)(unsigned)(ak & 0xFFFFFFFFu);

        float a1x = __shfl(pcx, id1), a1y = __shfl(pcy, id1), a1z = __shfl(pcz, id1);
        float n1 = sqrtf(a1x*a1x + a1y*a1y + a1z*a1z) + EPSF;
        a1x /= n1; a1y /= n1; a1z /= n1;

        float sx = pcx, sy = pcy, sz = pcz;
        for (int s = 32; s > 0; s >>= 1) {
            sx += __shfl_xor(sx, s); sy += __shfl_xor(sy, s); sz += __shfl_xor(sz, s);
        }
        float a2x = sx * (1.f/64.f), a2y = sy * (1.f/64.f), a2z = sz * (1.f/64.f);
        float n2 = sqrtf(a2x*a2x + a2y*a2y + a2z*a2z) + EPSF;
        a2x /= n2; a2y /= n2; a2z /= n2;

        float a3x = a1x + 1.5f*a2x, a3y = a1y + 1.5f*a2y, a3z = a1z + 1.5f*a2z;
        float n3 = sqrtf(a3x*a3x + a3y*a3y + a3z*a3z) + EPSF;
        a3x /= n3; a3y /= n3; a3z /= n3;

        float den = vn + EPSF;
        float f1 = (pcx*a1x + pcy*a1y + pcz*a1z) / den;
        float f2 = (pcx*a2x + pcy*a2y + pcz*a2z) / den;
        float f3 = (pcx*a3x + pcy*a3y + pcz*a3z) / den;
        feat_up[q*64 + lane] = make_float4(f1, f2, f3, vn);
    }
}

// ---------------- 5-layer MLP via bf16 MFMA + max over K ----------------
// Epilogue writes emb_up's RAW-RESHAPE view directly into conv3's B operand:
// reference emb channel cc at position p = E_flat[cc*8192 + p] where E is [N][64].
// For (point q, feature f): cc = q>>7, p = (q&127)*64 + f  ->  xb3[p*192 + cc].
#define BROW 72
__global__ __launch_bounds__(256) void mlp_kernel(
    const float4* __restrict__ feat_up,
    const unsigned short* __restrict__ gwt,
    unsigned short* __restrict__ xb3)
{
    __shared__ __align__(16) unsigned short Blds[4][64 * BROW];
    const int lane = threadIdx.x & 63;
    const int wid  = threadIdx.x >> 6;
    const int q = blockIdx.x * 4 + wid;
    const int c = lane & 15, g = lane >> 4;
    unsigned short* B = Blds[wid];

    {
        float4 f = feat_up[q*64 + lane];
        uint2 p0;
        p0.x = (unsigned)f2bf(f.x) | ((unsigned)f2bf(f.y) << 16);
        p0.y = (unsigned)f2bf(f.z) | ((unsigned)f2bf(f.w) << 16);
        *(uint2*)&B[lane*BROW] = p0;
        *(uint2*)&B[lane*BROW + 4] = make_uint2(0, 0);
        uint4 z4 = make_uint4(0, 0, 0, 0);
        *(uint4*)&B[lane*BROW + 8]  = z4;
        *(uint4*)&B[lane*BROW + 16] = z4;
        *(uint4*)&B[lane*BROW + 24] = z4;
    }

    const unsigned short* Wl[5] = {gwt, gwt + 2048, gwt + 6144, gwt + 10240, gwt + 14336};
    f32x4 acc[4][4];

    for (int layer = 0; layer < 5; ++layer) {
        const int wstride = (layer == 0) ? 32 : 64;
        const int nks = (layer == 0) ? 1 : 2;
        #pragma unroll
        for (int mb = 0; mb < 4; ++mb)
            #pragma unroll
            for (int nb = 0; nb < 4; ++nb)
                acc[mb][nb] = (f32x4){0.f, 0.f, 0.f, 0.f};

        for (int ks = 0; ks < nks; ++ks) {
            bf16x8 af[4], bf[4];
            #pragma unroll
            for (int mb = 0; mb < 4; ++mb)
                af[mb] = *(const bf16x8*)(Wl[layer] + (mb*16 + c)*wstride + ks*32 + g*8);
            #pragma unroll
            for (int nb = 0; nb < 4; ++nb)
                bf[nb] = *(const bf16x8*)&B[(nb*16 + c)*BROW + ks*32 + g*8];
            #pragma unroll
            for (int mb = 0; mb < 4; ++mb)
                #pragma unroll
                for (int nb = 0; nb < 4; ++nb)
                    acc[mb][nb] = __builtin_amdgcn_mfma_f32_16x16x32_bf16(af[mb], bf[nb], acc[mb][nb], 0, 0, 0);
        }

        if (layer < 4) {
            #pragma unroll
            for (int mb = 0; mb < 4; ++mb) {
                #pragma unroll
                for (int nb = 0; nb < 4; ++nb) {
                    f32x4 a = acc[mb][nb];
                    float r0 = fmaxf(a[0], 0.f), r1 = fmaxf(a[1], 0.f);
                    float r2 = fmaxf(a[2], 0.f), r3 = fmaxf(a[3], 0.f);
                    uint2 pw;
                    pw.x = (unsigned)f2bf(r0) | ((unsigned)f2bf(r1) << 16);
                    pw.y = (unsigned)f2bf(r2) | ((unsigned)f2bf(r3) << 16);
                    *(uint2*)&B[(nb*16 + c)*BROW + mb*16 + g*4] = pw;
                }
            }
        }
    }

    // epilogue: ReLU + max over neighbors; feature f = mb*16 + g*4 + r.
    // Write to raw-view location: xb3[((q&127)*64 + f)*192 + (q>>7)].
    const int cc = q >> 7;
    const int pbase = (q & 127) << 6;
    #pragma unroll
    for (int mb = 0; mb < 4; ++mb) {
        float v[4];
        #pragma unroll
        for (int r = 0; r < 4; ++r)
            v[r] = fmaxf(fmaxf(fmaxf(acc[mb][0][r], acc[mb][1][r]),
                               fmaxf(acc[mb][2][r], acc[mb][3][r])), 0.f);
        #pragma unroll
        for (int mask = 1; mask <= 8; mask <<= 1)
            #pragma unroll
            for (int r = 0; r < 4; ++r)
                v[r] = fmaxf(v[r], __shfl_xor(v[r], mask));
        if (c == 0) {
            #pragma unroll
            for (int r = 0; r < 4; ++r) {
                const int f = mb*16 + g*4 + r;
                xb3[(size_t)(pbase + f) * 192 + cc] = f2bf(v[r]);
            }
        }
    }
}

// ---------------- conv1 (fp32 GEMV, K=4) with output stats ----------------
__global__ __launch_bounds__(256) void conv1_kernel(
    const float* __restrict__ x, const float* __restrict__ wt,
    const float* __restrict__ bias, float* __restrict__ y,
    float* __restrict__ stout)
{
    const int tid = threadIdx.x;
    const int p  = blockIdx.x * 256 + tid;
    const int o0 = blockIdx.y * 32;
    float acc[32];
    #pragma unroll
    for (int u = 0; u < 32; ++u) acc[u] = bias[o0 + u];
    #pragma unroll
    for (int c = 0; c < 4; ++c) {
        float xv = x[c * NPTS + p];
        const float* wr = wt + c * 64 + o0;
        #pragma unroll
        for (int u = 0; u < 32; ++u) acc[u] = fmaf(xv, wr[u], acc[u]);
    }
    #pragma unroll
    for (int u = 0; u < 32; ++u) y[(o0 + u) * NPTS + p] = acc[u];

    __shared__ float ps[4][32], pss[4][32];
    const int wid = tid >> 6, lane = tid & 63;
    #pragma unroll
    for (int u = 0; u < 32; ++u) {
        float s = acc[u], ss = acc[u] * acc[u];
        for (int j = 32; j > 0; j >>= 1) { s += __shfl_xor(s, j); ss += __shfl_xor(ss, j); }
        if (lane == 0) { ps[wid][u] = s; pss[wid][u] = ss; }
    }
    __syncthreads();
    if (tid < 32) {
        float S  = ps[0][tid] + ps[1][tid] + ps[2][tid] + ps[3][tid];
        float SS = pss[0][tid] + pss[1][tid] + pss[2][tid] + pss[3][tid];
        atomicAdd(&stout[o0 + tid], S);
        atomicAdd(&stout[64 + o0 + tid], SS);
    }
}

// ---------------- bnpack: y fp32 [C][N] -> BN+ReLU -> bf16 xb[p][stride] at col offset ----------------
__global__ __launch_bounds__(256) void bnpack_kernel(
    const float* __restrict__ y, const float* __restrict__ st,
    const float* __restrict__ gam, const float* __restrict__ bet,
    int C, int stride, int coff, unsigned short* __restrict__ xb)
{
    __shared__ float sc[256], sh[256];
    __shared__ __align__(16) unsigned short tile[64][264];
    const int tid = threadIdx.x;
    for (int cc = tid; cc < C; cc += 256) {
        float mu  = st[cc] * (1.f / 8192.f);
        float var = st[C + cc] * (1.f / 8192.f) - mu * mu;
        float s = gam[cc] / sqrtf(var + 1e-5f);
        sc[cc] = s; sh[cc] = bet[cc] - mu * s;
    }
    __syncthreads();
    const int pl = tid & 63, g = tid >> 6;
    const int p = blockIdx.x * 64 + pl;
    for (int c0 = g * 8; c0 < C; c0 += 32) {
        unsigned pk[4];
        #pragma unroll
        for (int h = 0; h < 4; ++h) {
            float v0 = fmaxf(fmaf(y[(c0 + 2*h    ) * NPTS + p], sc[c0 + 2*h    ], sh[c0 + 2*h    ]), 0.f);
            float v1 = fmaxf(fmaf(y[(c0 + 2*h + 1) * NPTS + p], sc[c0 + 2*h + 1], sh[c0 + 2*h + 1]), 0.f);
            pk[h] = (unsigned)f2bf(v0) | ((unsigned)f2bf(v1) << 16);
        }
        *(uint4*)&tile[pl][c0] = make_uint4(pk[0], pk[1], pk[2], pk[3]);
    }
    __syncthreads();
    const int cpr = C >> 3;                 // 16B chunks per row
    const int nch = 64 * cpr;
    for (int idx = tid; idx < nch; idx += 256) {
        int r = idx / cpr, cc = (idx - r * cpr) * 8;
        *(uint4*)&xb[(size_t)(blockIdx.x * 64 + r) * stride + coff + cc] = *(uint4*)&tile[r][cc];
    }
}

// ---------------- conv via MFMA: y[M][N] = A[M][K](bf16) x Xb[N][K](bf16)^T + bias ----------------
__global__ __launch_bounds__(256) void conv_mfma_kernel(
    const unsigned short* __restrict__ A, const unsigned short* __restrict__ Bx,
    const float* __restrict__ bias, int K, int M,
    float* __restrict__ y, float* __restrict__ stout)
{
    const int lane = threadIdx.x & 63;
    const int w = threadIdx.x >> 6;
    const int n0 = blockIdx.x * 256 + w * 64;
    const int m0 = blockIdx.y * 64;
    const int c = lane & 15, g = lane >> 4;

    f32x4 acc[4][4];
    #pragma unroll
    for (int mt = 0; mt < 4; ++mt)
        #pragma unroll
        for (int nt = 0; nt < 4; ++nt)
            acc[mt][nt] = (f32x4){0.f, 0.f, 0.f, 0.f};

    for (int k0 = 0; k0 < K; k0 += 32) {
        bf16x8 af[4], bf[4];
        #pragma unroll
        for (int mt = 0; mt < 4; ++mt)
            af[mt] = *(const bf16x8*)(A + (size_t)(m0 + mt*16 + c) * K + k0 + g*8);
        #pragma unroll
        for (int nt = 0; nt < 4; ++nt)
            bf[nt] = *(const bf16x8*)(Bx + (size_t)(n0 + nt*16 + c) * K + k0 + g*8);
        #pragma unroll
        for (int mt = 0; mt < 4; ++mt)
            #pragma unroll
            for (int nt = 0; nt < 4; ++nt)
                acc[mt][nt] = __builtin_amdgcn_mfma_f32_16x16x32_bf16(af[mt], bf[nt], acc[mt][nt], 0, 0, 0);
    }

    #pragma unroll
    for (int mt = 0; mt < 4; ++mt) {
        float s[4], ss[4];
        #pragma unroll
        for (int r = 0; r < 4; ++r) {
            const int o = m0 + mt*16 + g*4 + r;
            const float bv = bias[o];
            float sum = 0.f, sq = 0.f;
            #pragma unroll
            for (int nt = 0; nt < 4; ++nt) {
                float v = acc[mt][nt][r] + bv;
                y[(size_t)o * NPTS + n0 + nt*16 + c] = v;
                sum += v; sq += v * v;
            }
            s[r] = sum; ss[r] = sq;
        }
        #pragma unroll
        for (int mask = 1; mask <= 8; mask <<= 1)
            #pragma unroll
            for (int r = 0; r < 4; ++r) {
                s[r]  += __shfl_xor(s[r],  mask);
                ss[r] += __shfl_xor(ss[r], mask);
            }
        if (c == 0) {
            #pragma unroll
            for (int r = 0; r < 4; ++r) {
                const int o = m0 + mt*16 + g*4 + r;
                atomicAdd(&stout[o], s[r]);
                atomicAdd(&stout[M + o], ss[r]);
            }
        }
    }
}

// ---------------- final BN + ReLU (in place on d_out) ----------------
__global__ __launch_bounds__(256) void bnrelu_kernel(
    const float* y, const float* __restrict__ st,
    const float* __restrict__ g, const float* __restrict__ b,
    float* out, int C)
{
    int idx = blockIdx.x * 256 + threadIdx.x;
    int c = idx >> 13;   // N = 8192
    float mu  = st[c] * (1.f / 8192.f);
    float var = st[C + c] * (1.f / 8192.f) - mu * mu;
    float scale = g[c] / sqrtf(var + 1e-5f);
    float v = fmaf(y[idx] - mu, scale, b[c]);
    out[idx] = fmaxf(v, 0.f);
}

extern "C" void kernel_launch(void* const* d_in, const int* in_sizes, int n_in,
                              void* d_out, int out_size, void* d_ws, size_t ws_size,
                              hipStream_t stream) {
    const float* points = (const float*)d_in[0];
    const float* gw0 = (const float*)d_in[1];
    const float* gw1 = (const float*)d_in[2];
    const float* gw2 = (const float*)d_in[3];
    const float* gw3 = (const float*)d_in[4];
    const float* gw4 = (const float*)d_in[5];
    const float* c1w = (const float*)d_in[6];  const float* c1b = (const float*)d_in[7];
    const float* bn1g = (const float*)d_in[8]; const float* bn1b = (const float*)d_in[9];
    const float* c2w = (const float*)d_in[10]; const float* c2b = (const float*)d_in[11];
    const float* bn2g = (const float*)d_in[12];const float* bn2b = (const float*)d_in[13];
    const float* c3w = (const float*)d_in[14]; const float* c3b = (const float*)d_in[15];
    const float* bn3g = (const float*)d_in[16];const float* bn3b = (const float*)d_in[17];
    const float* c4w = (const float*)d_in[18]; const float* c4b = (const float*)d_in[19];
    const float* bn4g = (const float*)d_in[20];const float* bn4b = (const float*)d_in[21];

    float* ws = (float*)d_ws;
    float* p4f    = ws + OFF_P4;
    float* featdn = ws + OFF_FEATDN;
    float* featup = ws + OFF_FEATUP;
    float* y1 = ws + OFF_Y1; float* y2 = ws + OFF_Y2; float* y3 = ws + OFF_Y3;
    float* s1 = ws + OFF_STATS + 0;
    float* s2 = ws + OFF_STATS + 128;
    float* s3 = ws + OFF_STATS + 384;
    float* s4 = ws + OFF_STATS + 896;
    float* wt1 = ws + OFF_WT1;
    const unsigned short* gwt = (const unsigned short*)(ws + OFF_GWT);
    const unsigned short* bw2 = (const unsigned short*)(ws + OFF_BW2);
    const unsigned short* bw3 = (const unsigned short*)(ws + OFF_BW3);
    const unsigned short* bw4 = (const unsigned short*)(ws + OFF_BW4);
    unsigned short* xb1 = (unsigned short*)(ws + OFF_XB1);
    unsigned short* xb3 = (unsigned short*)(ws + OFF_XB3);
    unsigned short* xb4 = (unsigned short*)(ws + OFF_XB4);
    float* outp = (float*)d_out;

    prep_a_kernel<<<32, 256, 0, stream>>>(points, ws);
    prep_b_kernel<<<1, 64, 0, stream>>>(points, ws);
    prep_c_kernel<<<32, 256, 0, stream>>>(ws);
    wt_kernel<<<256, 256, 0, stream>>>(c1w, c2w, c3w, c4w, gw0, gw1, gw2, gw3, gw4, ws);

    knn_feat_kernel<<<512, 512, 0, stream>>>((const float4*)p4f, (float4*)featup);
    mlp_kernel<<<2048, 256, 0, stream>>>((const float4*)featup, gwt, xb3);

    // conv1 (fp32, K=4) -> y1 + s1
    conv1_kernel<<<dim3(32, 2), 256, 0, stream>>>(featdn, wt1, c1b, y1, s1);
    // BN1+ReLU -> xb1[p][64]
    bnpack_kernel<<<128, 256, 0, stream>>>(y1, s1, bn1g, bn1b, 64, 64, 0, xb1);
    // conv2: 128x64x8192 MFMA -> y2 + s2
    conv_mfma_kernel<<<dim3(32, 2), 256, 0, stream>>>(bw2, xb1, c2b, 64, 128, y2, s2);
    // BN2+ReLU -> xb3[p][192] cols 64..191 (cols 0..63 = raw-view emb_up from mlp)
    bnpack_kernel<<<128, 256, 0, stream>>>(y2, s2, bn2g, bn2b, 128, 192, 64, xb3);
    // conv3: 256x192x8192 MFMA -> y3 + s3
    conv_mfma_kernel<<<dim3(32, 4), 256, 0, stream>>>(bw3, xb3, c3b, 192, 256, y3, s3);
    // BN3+ReLU -> xb4[p][256]
    bnpack_kernel<<<128, 256, 0, stream>>>(y3, s3, bn3g, bn3b, 256, 256, 0, xb4);
    // conv4: 1024x256x8192 MFMA -> d_out (pre-BN) + s4
    conv_mfma_kernel<<<dim3(32, 16), 256, 0, stream>>>(bw4, xb4, c4b, 256, 1024, outp, s4);
    // final BN4 + ReLU in place
    bnrelu_kernel<<<1024*32, 256, 0, stream>>>(outp, s4, bn4g, bn4b, outp, 1024);
}